// Round 12
// baseline (802.184 us; speedup 1.0000x reference)
//
#include <hip/hip_runtime.h>
#include <hip/hip_fp16.h>

#define L_ 2048
#define NROW 16384
#define FIN 1038

// ---------------- node embedding part: Part[split] = X[:, ks:ke] @ W[ks:ke, :] ----------------
__global__ __launch_bounds__(256) void k_node_part(const float* __restrict__ X,
                                                   const float* __restrict__ W,
                                                   float* __restrict__ Part) {
  const int rb = blockIdx.x >> 2;
  const int split = blockIdx.x & 3;
  const int kStart = split * 260;
  const int kEnd = (split == 3) ? FIN : (kStart + 260);
  const int t = threadIdx.x;
  const int row0 = rb * 128;
  __shared__ float Xs[2][16][132];
  __shared__ float Ws[2][16][64];
  const int ri = t >> 3;
  const int ci = t & 7;
  const int sxr = t >> 2;
  const int sxk = (t & 3) * 4;
  const int swr = t >> 4;
  const int swc = (t & 15) * 4;

  float acc[4][8];
#pragma unroll
  for (int u = 0; u < 4; u++)
#pragma unroll
    for (int v = 0; v < 8; v++) acc[u][v] = 0.f;

  float4 px0, px1, pwv;

#define LOADX(dst, kc, rsub)                                            \
  {                                                                     \
    const int col = (kc) + sxk;                                         \
    const float* xr = &X[(size_t)(row0 + sxr + 64 * (rsub)) * FIN];     \
    float4 v = make_float4(0.f, 0.f, 0.f, 0.f);                         \
    if (col + 4 <= kEnd) v = *(const float4*)&xr[col];                  \
    else {                                                              \
      if (col + 0 < kEnd) v.x = xr[col + 0];                            \
      if (col + 1 < kEnd) v.y = xr[col + 1];                            \
      if (col + 2 < kEnd) v.z = xr[col + 2];                            \
      if (col + 3 < kEnd) v.w = xr[col + 3];                            \
    }                                                                   \
    dst = v;                                                            \
  }
#define LOADW(dst, kc)                                                  \
  {                                                                     \
    const int j = (kc) + swr;                                           \
    dst = (j < kEnd) ? *(const float4*)&W[(size_t)j * 64 + swc]         \
                     : make_float4(0.f, 0.f, 0.f, 0.f);                 \
  }

  LOADX(px0, kStart, 0);
  LOADX(px1, kStart, 1);
  LOADW(pwv, kStart);

  int buf = 0;
  for (int kc = kStart; kc < kEnd; kc += 16) {
    Xs[buf][sxk + 0][sxr] = px0.x;
    Xs[buf][sxk + 1][sxr] = px0.y;
    Xs[buf][sxk + 2][sxr] = px0.z;
    Xs[buf][sxk + 3][sxr] = px0.w;
    Xs[buf][sxk + 0][64 + sxr] = px1.x;
    Xs[buf][sxk + 1][64 + sxr] = px1.y;
    Xs[buf][sxk + 2][64 + sxr] = px1.z;
    Xs[buf][sxk + 3][64 + sxr] = px1.w;
    *(float4*)&Ws[buf][swr][swc] = pwv;
    __syncthreads();
    const int kn = kc + 16;
    if (kn < kEnd) {
      LOADX(px0, kn, 0);
      LOADX(px1, kn, 1);
      LOADW(pwv, kn);
    }
#pragma unroll
    for (int k = 0; k < 16; k++) {
      const float4 xv = *(const float4*)&Xs[buf][k][4 * ri];
      const float4 w0 = *(const float4*)&Ws[buf][k][8 * ci];
      const float4 w1 = *(const float4*)&Ws[buf][k][8 * ci + 4];
      const float xr_[4] = {xv.x, xv.y, xv.z, xv.w};
      const float wc_[8] = {w0.x, w0.y, w0.z, w0.w, w1.x, w1.y, w1.z, w1.w};
#pragma unroll
      for (int u = 0; u < 4; u++)
#pragma unroll
        for (int v = 0; v < 8; v++) acc[u][v] += xr_[u] * wc_[v];
    }
    buf ^= 1;
  }
#undef LOADX
#undef LOADW

  float* P = Part + (size_t)split * (NROW * 64);
#pragma unroll
  for (int u = 0; u < 4; u++) {
    const int row = row0 + 4 * ri + u;
    *(float4*)&P[(size_t)row * 64 + 8 * ci] =
        make_float4(acc[u][0], acc[u][1], acc[u][2], acc[u][3]);
    *(float4*)&P[(size_t)row * 64 + 8 * ci + 4] =
        make_float4(acc[u][4], acc[u][5], acc[u][6], acc[u][7]);
  }
}

// ---------------- hV = sum of 4 partials + bias ----------------
__global__ __launch_bounds__(256) void k_node_sum(const float* __restrict__ Part,
                                                  const float* __restrict__ bias,
                                                  float* __restrict__ out) {
  const int i = (blockIdx.x * 256 + threadIdx.x) * 4;
  const float4 a = *(const float4*)&Part[i];
  const float4 b = *(const float4*)&Part[1048576 + i];
  const float4 c = *(const float4*)&Part[2 * 1048576 + i];
  const float4 d = *(const float4*)&Part[3 * 1048576 + i];
  const float4 bb = *(const float4*)&bias[i & 63];
  float4 o;
  o.x = a.x + b.x + c.x + d.x + bb.x;
  o.y = a.y + b.y + c.y + d.y + bb.y;
  o.z = a.z + b.z + c.z + d.z + bb.z;
  o.w = a.w + b.w + c.w + d.w + bb.w;
  *(float4*)&out[i] = o;
}

// ---------------- edges: distances + histogram-select top-30 + E_ln precompute (R9 proven) ----------------
__global__ __launch_bounds__(256) void k_edges(const float* __restrict__ coords,
                                               const float* __restrict__ mask,
                                               const float* __restrict__ Wee,
                                               const float* __restrict__ geln,
                                               const float* __restrict__ beln,
                                               int* __restrict__ Eidx,
                                               __half* __restrict__ Eln) {
  const int row = blockIdx.x;
  const int b = row >> 11;
  const int t = threadIdx.x;
  const int lane = t & 63, wid = t >> 6;
  __shared__ float sredf[4];
  __shared__ unsigned int hist[2048];
  __shared__ unsigned int wtot[4];
  __shared__ int s_bin, s_need;
  __shared__ int s_lcnt, s_outcnt;
  __shared__ unsigned int s_lkey[64];
  __shared__ int s_lidx[64];
  __shared__ int s_sel[64];
  __shared__ float sD[30];
  __shared__ int sJ[30];
  __shared__ float sWee[16][16];
  __shared__ float sg[16], sb[16];
  __shared__ float sRBF[30][16];

  if (t < 256) sWee[t >> 4][t & 15] = Wee[t];
  if (t < 16) { sg[t] = geln[t]; sb[t] = beln[t]; }
  if (t == 0) { s_lcnt = 0; s_outcnt = 0; }

  const float* cb = coords + (size_t)b * (L_ * 3);
  const int i = row & (L_ - 1);
  const float cix = cb[i * 3 + 0], ciy = cb[i * 3 + 1], ciz = cb[i * 3 + 2];
  const float mi = mask[row];
  const float* mb = mask + (size_t)b * L_;
  float d[8], mj[8];
  float dmax = 0.f;
#pragma unroll
  for (int u = 0; u < 8; u++) {
    int j = t + 256 * u;
    float dx = cix - cb[j * 3 + 0];
    float dy = ciy - cb[j * 3 + 1];
    float dz = ciz - cb[j * 3 + 2];
    float dist = sqrtf(dx * dx + dy * dy + dz * dz + 1e-6f);
    d[u] = dist;
    mj[u] = mb[j];
    dmax = fmaxf(dmax, dist);
  }
#pragma unroll
  for (int off = 32; off; off >>= 1) dmax = fmaxf(dmax, __shfl_xor(dmax, off, 64));
  if (lane == 0) sredf[wid] = dmax;
#pragma unroll
  for (int q = 0; q < 8; q++) hist[t * 8 + q] = 0u;
  __syncthreads();
  dmax = fmaxf(fmaxf(sredf[0], sredf[1]), fmaxf(sredf[2], sredf[3]));
  const float scale = 1024.0f / fmaxf(dmax, 1e-20f);
  float adj[8];
  int bin[8];
#pragma unroll
  for (int u = 0; u < 8; u++) {
    adj[u] = d[u] + (1.f - mi * mj[u]) * dmax;
    int bi = (int)(adj[u] * scale);
    bin[u] = bi < 2047 ? bi : 2047;
    atomicAdd(&hist[bin[u]], 1u);
  }
  __syncthreads();
  unsigned int c[8];
  unsigned int local = 0;
#pragma unroll
  for (int q = 0; q < 8; q++) { c[q] = hist[t * 8 + q]; local += c[q]; }
  unsigned int incl = local;
#pragma unroll
  for (int off = 1; off < 64; off <<= 1) {
    unsigned int v = __shfl_up(incl, off, 64);
    if (lane >= off) incl += v;
  }
  if (lane == 63) wtot[wid] = incl;
  __syncthreads();
  unsigned int excl = incl - local;
  for (int w = 0; w < wid; w++) excl += wtot[w];
  if (excl < 30u && excl + local >= 30u) {
    unsigned int run = excl;
#pragma unroll
    for (int q = 0; q < 8; q++) {
      if (run + c[q] >= 30u) { s_bin = t * 8 + q; s_need = 30 - (int)run; break; }
      run += c[q];
    }
  }
  __syncthreads();
  const int tbin = s_bin;
  int pos[8];
#pragma unroll
  for (int u = 0; u < 8; u++) {
    pos[u] = -1;
    if (bin[u] == tbin) {
      int p = atomicAdd(&s_lcnt, 1);
      if (p < 64) { s_lkey[p] = __float_as_uint(adj[u]); s_lidx[p] = t + 256 * u; pos[u] = p; }
    }
  }
  __syncthreads();
  {
    int n = s_lcnt < 64 ? s_lcnt : 64;
    if (t < n) {
      unsigned int k0 = s_lkey[t];
      int j0 = s_lidx[t];
      int r = 0;
      for (int m = 0; m < n; m++) {
        unsigned int km = s_lkey[m];
        r += (km < k0) || (km == k0 && s_lidx[m] < j0);
      }
      s_sel[t] = (r < s_need) ? 1 : 0;
    }
  }
  __syncthreads();
#pragma unroll
  for (int u = 0; u < 8; u++) {
    bool sel = (bin[u] < tbin) || (pos[u] >= 0 && s_sel[pos[u]]);
    if (sel) {
      int o = atomicAdd(&s_outcnt, 1);
      if (o < 30) { sJ[o] = t + 256 * u; sD[o] = adj[u]; }
    }
  }
  __syncthreads();
  if (t < 30) Eidx[(size_t)row * 30 + t] = sJ[t];
  for (int o = t; o < 480; o += 256) {
    int k = o >> 4, s = o & 15;
    float mu = 2.0f + (4.0f / 3.0f) * (float)s;
    float z = (sD[k] - mu) * 0.8f;
    sRBF[k][s] = __expf(-z * z);
  }
  __syncthreads();
  if (t < 240) {
    int k = t >> 3, p = t & 7;
    int c0 = p * 2, c1 = c0 + 1;
    float e0 = 0.f, e1 = 0.f;
#pragma unroll
    for (int s = 0; s < 16; s++) {
      float r = sRBF[k][s];
      e0 += r * sWee[s][c0];
      e1 += r * sWee[s][c1];
    }
    float s1 = e0 + e1, s2 = e0 * e0 + e1 * e1;
#pragma unroll
    for (int m = 1; m < 8; m <<= 1) {
      s1 += __shfl_xor(s1, m, 64);
      s2 += __shfl_xor(s2, m, 64);
    }
    float mean = s1 * (1.f / 16.f);
    float var = s2 * (1.f / 16.f) - mean * mean;
    float inv = rsqrtf(var + 1e-5f);
    Eln[(size_t)row * 480 + k * 16 + c0] = __float2half((e0 - mean) * inv * sg[c0] + sb[c0]);
    Eln[(size_t)row * 480 + k * 16 + c1] = __float2half((e1 - mean) * inv * sg[c1] + sb[c1]);
  }
}

// ---------------- per-layer weight folding ----------------
__global__ __launch_bounds__(256) void k_prep(const float* __restrict__ Wep,
                                              const float* __restrict__ bep,
                                              const float* __restrict__ WK,
                                              const float* __restrict__ bK,
                                              const float* __restrict__ WV,
                                              const float* __restrict__ bV,
                                              float* __restrict__ WKfold,
                                              float* __restrict__ bK2,
                                              float* __restrict__ WepWV,
                                              float* __restrict__ bV2) {
  const int l = blockIdx.x >> 1, isV = blockIdx.x & 1;
  const float* W = (isV ? WV : WK) + (size_t)l * 8192;
  const float* bsrc = (isV ? bV : bK) + l * 64;
  float* fold = (isV ? WepWV : WKfold) + l * 1024;
  float* b2 = (isV ? bV2 : bK2) + l * 64;
  __shared__ float sW[64][64];
  __shared__ float sWep[16][64];
  const int t = threadIdx.x;
  for (int q = 0; q < 16; q++) { int i = t + 256 * q; sW[i >> 6][i & 63] = W[i]; }
  for (int q = 0; q < 4; q++)  { int i = t + 256 * q; sWep[i >> 6][i & 63] = Wep[i]; }
  __syncthreads();
  const int c = t & 63, rg = t >> 6;
  for (int r = rg; r < 16; r += 4) {
    float a = 0.f;
    for (int s = 0; s < 64; s++) a += sWep[r][s] * sW[s][c];
    fold[r * 64 + c] = a;
  }
  if (t < 64) {
    float a = bsrc[t];
    for (int s = 0; s < 64; s++) a += bep[s] * sW[s][t];
    b2[t] = a;
  }
}

// ---------------- k_qproj: fused Q=hV@WQ+bQ (LDS) -> QWn/eqw/qb2; 512 blocks x 32 rows ----------------
__global__ __launch_bounds__(256) void k_qproj(const float* __restrict__ hV,
                                               const float* __restrict__ WQ,
                                               const float* __restrict__ bQ,
                                               const float* __restrict__ WK,
                                               const float* __restrict__ WKfold,
                                               const float* __restrict__ bK2,
                                               float* __restrict__ QWn,
                                               float* __restrict__ eqw,
                                               float* __restrict__ qb2) {
  __shared__ float sX[32 * 68];
  __shared__ float sW[64 * 64];  // phase 1: WQ row-major; reused after barrier as sQ[32*68]
  __shared__ float sb[64];
  const int t = threadIdx.x;
  const int row0 = blockIdx.x * 32;
  const int c = t & 63, rg = t >> 6;
  const int h = t >> 6, s2 = t & 63;
  const float4 wk0 = *(const float4*)&WK[(size_t)(64 + s2) * 64 + h * 16 + 0];
  const float4 wk1 = *(const float4*)&WK[(size_t)(64 + s2) * 64 + h * 16 + 4];
  const float4 wk2 = *(const float4*)&WK[(size_t)(64 + s2) * 64 + h * 16 + 8];
  const float4 wk3 = *(const float4*)&WK[(size_t)(64 + s2) * 64 + h * 16 + 12];
  const int rb4 = (t >> 4) & 3, tt = t & 15;
  const float4 wf0 = *(const float4*)&WKfold[tt * 64 + h * 16 + 0];
  const float4 wf1 = *(const float4*)&WKfold[tt * 64 + h * 16 + 4];
  const float4 wf2 = *(const float4*)&WKfold[tt * 64 + h * 16 + 8];
  const float4 wf3 = *(const float4*)&WKfold[tt * 64 + h * 16 + 12];
#pragma unroll
  for (int q = 0; q < 8; q++) {
    int i = t + 256 * q;
    sX[(i >> 6) * 68 + (i & 63)] = hV[(size_t)(row0 + (i >> 6)) * 64 + (i & 63)];
  }
#pragma unroll
  for (int q = 0; q < 16; q++) {
    int i = t + 256 * q;
    sW[i] = WQ[i];
  }
  if (t < 64) sb[t] = bK2[t];
  __syncthreads();
  float acc[8];
#pragma unroll
  for (int u = 0; u < 8; u++) acc[u] = 0.f;
#pragma unroll
  for (int s0 = 0; s0 < 64; s0 += 4) {
    float w0 = sW[s0 * 64 + c], w1 = sW[(s0 + 1) * 64 + c];
    float w2 = sW[(s0 + 2) * 64 + c], w3 = sW[(s0 + 3) * 64 + c];
#pragma unroll
    for (int u = 0; u < 8; u++) {
      const float4 a = *(const float4*)&sX[(rg + 4 * u) * 68 + s0];
      acc[u] += a.x * w0 + a.y * w1 + a.z * w2 + a.w * w3;
    }
  }
  __syncthreads();
  const float bb = bQ[c];
  float* sQ = sW;
#pragma unroll
  for (int u = 0; u < 8; u++) sQ[(rg + 4 * u) * 68 + c] = acc[u] + bb;
  __syncthreads();
  for (int r = 0; r < 32; r++) {
    const float4 q0 = *(const float4*)&sQ[r * 68 + h * 16 + 0];
    const float4 q1 = *(const float4*)&sQ[r * 68 + h * 16 + 4];
    const float4 q2 = *(const float4*)&sQ[r * 68 + h * 16 + 8];
    const float4 q3 = *(const float4*)&sQ[r * 68 + h * 16 + 12];
    float a = q0.x * wk0.x + q0.y * wk0.y + q0.z * wk0.z + q0.w * wk0.w
            + q1.x * wk1.x + q1.y * wk1.y + q1.z * wk1.z + q1.w * wk1.w
            + q2.x * wk2.x + q2.y * wk2.y + q2.z * wk2.z + q2.w * wk2.w
            + q3.x * wk3.x + q3.y * wk3.y + q3.z * wk3.z + q3.w * wk3.w;
    QWn[(size_t)(row0 + r) * 256 + h * 64 + s2] = a;
  }
  for (int rr = 0; rr < 8; rr++) {
    const int r = rr * 4 + rb4;
    const float4 q0 = *(const float4*)&sQ[r * 68 + h * 16 + 0];
    const float4 q1 = *(const float4*)&sQ[r * 68 + h * 16 + 4];
    const float4 q2 = *(const float4*)&sQ[r * 68 + h * 16 + 8];
    const float4 q3 = *(const float4*)&sQ[r * 68 + h * 16 + 12];
    float a = q0.x * wf0.x + q0.y * wf0.y + q0.z * wf0.z + q0.w * wf0.w
            + q1.x * wf1.x + q1.y * wf1.y + q1.z * wf1.z + q1.w * wf1.w
            + q2.x * wf2.x + q2.y * wf2.y + q2.z * wf2.z + q2.w * wf2.w
            + q3.x * wf3.x + q3.y * wf3.y + q3.z * wf3.z + q3.w * wf3.w;
    eqw[(size_t)(row0 + r) * 64 + h * 16 + tt] = a;
  }
  if (t < 128) {
    const int r = t >> 2, h2 = t & 3;
    float a = 0.f;
#pragma unroll
    for (int d = 0; d < 16; d++) a += sQ[r * 68 + h2 * 16 + d] * sb[h2 * 16 + d];
    qb2[(size_t)(row0 + r) * 4 + h2] = a;
  }
}

// ---------------- k_attn v3: split-k P-phase + vectorized global staging ----------------
__global__ __launch_bounds__(256) void k_attn(
    const __half* __restrict__ Eln, const int* __restrict__ Eidx,
    const float* __restrict__ hV, const float* __restrict__ mask,
    const float* __restrict__ QWn, const float* __restrict__ eqw,
    const float* __restrict__ qb2,
    float* __restrict__ Pg, float* __restrict__ attsum) {
  const int row = blockIdx.x;
  const int b = row >> 11;
  const int t = threadIdx.x;
  const int lane = t & 63, wid = t >> 6;
  __shared__ float sHV[30 * 65];
  __shared__ float sE[30 * 17];
  __shared__ float sQn[256];
  __shared__ float swq[64];
  __shared__ float sqb2[4];
  __shared__ float smk[32];
  __shared__ float satt4[32 * 4];
  __shared__ float sPc[4][4][64];
  __shared__ float sEc[4][4][16];

  sQn[t] = QWn[(size_t)row * 256 + t];
  if (t < 64) swq[t] = eqw[(size_t)row * 64 + t];
  if (t < 4) sqb2[t] = qb2[(size_t)row * 4 + t];
  if (t < 30) smk[t] = mask[(b << 11) + Eidx[(size_t)row * 30 + t]] * mask[row];
  if (t < 240) {
    const __half2 h2v = *(const __half2*)&Eln[(size_t)row * 480 + 2 * t];
    const float2 f2 = __half22float2(h2v);
    const int k = (2 * t) >> 4, c = (2 * t) & 15;
    sE[k * 17 + c] = f2.x;
    sE[k * 17 + c + 1] = f2.y;
  }
#pragma unroll
  for (int q = 0; q < 4; q++) {
    int o = t + 256 * q;
    if (o < 960) {
      const int k = o >> 5, c2 = (o & 31) * 2;
      const int j = Eidx[(size_t)row * 30 + k];
      const float2 v = *(const float2*)&hV[((size_t)(b << 11) + j) * 64 + c2];
      sHV[k * 65 + c2] = v.x;
      sHV[k * 65 + c2 + 1] = v.y;
    }
  }
  __syncthreads();

  const int kk = (lane < 30) ? lane : (lane - 30);
  const int sbase = (lane < 30) ? 0 : 32;
  const int tbase = (lane < 30) ? 0 : 8;
  float lg = 0.f;
  if (lane < 60) {
#pragma unroll
    for (int s = 0; s < 32; s++)
      lg += sHV[kk * 65 + sbase + s] * sQn[wid * 64 + sbase + s];
#pragma unroll
    for (int tt = 0; tt < 8; tt++)
      lg += sE[kk * 17 + tbase + tt] * swq[wid * 16 + tbase + tt];
  }
  float oth = __shfl(lg, lane + 30, 64);
  float mk = (lane < 30) ? smk[lane] : 0.f;
  float lgv = (lane < 30 && mk > 0.f) ? (lg + oth + sqb2[wid]) * 0.25f
                                      : -3.402823466e38f;
  float mx = lgv;
#pragma unroll
  for (int off = 16; off; off >>= 1) mx = fmaxf(mx, __shfl_xor(mx, off, 64));
  float e = (lane < 30) ? __expf(lgv - mx) : 0.f;
  float den = e;
#pragma unroll
  for (int off = 16; off; off >>= 1) den += __shfl_xor(den, off, 64);
  float att = e * (1.f / den) * mk;
  float ss = att;
#pragma unroll
  for (int off = 16; off; off >>= 1) ss += __shfl_xor(ss, off, 64);
  if (lane == 0) attsum[(size_t)row * 4 + wid] = ss;
  if (lane < 30) satt4[lane * 4 + wid] = att;
  __syncthreads();

  const int k0 = wid * 8;
  const int knum = (wid == 3) ? 6 : 8;
  float pn0 = 0.f, pn1 = 0.f, pn2 = 0.f, pn3 = 0.f;
  float ea0 = 0.f, ea1 = 0.f, ea2 = 0.f, ea3 = 0.f;
  for (int u = 0; u < knum; u++) {
    const int k2 = k0 + u;
    const float4 a4 = *(const float4*)&satt4[k2 * 4];
    const float hvv = sHV[k2 * 65 + lane];
    pn0 += a4.x * hvv; pn1 += a4.y * hvv; pn2 += a4.z * hvv; pn3 += a4.w * hvv;
    const float ev = (lane < 16) ? sE[k2 * 17 + lane] : 0.f;
    ea0 += a4.x * ev; ea1 += a4.y * ev; ea2 += a4.z * ev; ea3 += a4.w * ev;
  }
  sPc[wid][0][lane] = pn0;
  sPc[wid][1][lane] = pn1;
  sPc[wid][2][lane] = pn2;
  sPc[wid][3][lane] = pn3;
  if (lane < 16) {
    sEc[wid][0][lane] = ea0;
    sEc[wid][1][lane] = ea1;
    sEc[wid][2][lane] = ea2;
    sEc[wid][3][lane] = ea3;
  }
  __syncthreads();
  float pv = sPc[0][wid][lane] + sPc[1][wid][lane] + sPc[2][wid][lane] + sPc[3][wid][lane];
  float* pr = Pg + (size_t)row * 320 + wid * 80;
  pr[lane] = pv;
  if (lane < 16) {
    float ev2 = sEc[0][wid][lane] + sEc[1][wid][lane] + sEc[2][wid][lane] + sEc[3][wid][lane];
    pr[64 + lane] = ev2;
  }
}

// ---------------- upd = Pnode @ WV_bot + eatt @ WepWV + ats*bV2 ----------------
__global__ __launch_bounds__(256) void k_upd(const float* __restrict__ Pg,
                                             const float* __restrict__ ats,
                                             const float* __restrict__ WV,
                                             const float* __restrict__ WepWV,
                                             const float* __restrict__ bV2,
                                             float* __restrict__ U) {
  __shared__ float sWVb[64 * 64];
  __shared__ float sWf[16 * 64];
  __shared__ float sb[64];
  __shared__ float sP[8 * 320];
  const int t = threadIdx.x;
  const int row0 = blockIdx.x * 8;
  for (int q = 0; q < 16; q++) {
    int i = t + 256 * q;
    sWVb[i] = WV[4096 + i];
  }
  for (int q = 0; q < 4; q++) {
    int i = t + 256 * q;
    sWf[i] = WepWV[i];
  }
  if (t < 64) sb[t] = bV2[t];
  for (int q = 0; q < 10; q++) {
    int i = t + 256 * q;
    sP[i] = Pg[(size_t)row0 * 320 + i];
  }
  __syncthreads();
  const int c = t & 63, rg = t >> 6;
  const int h = c >> 4;
  const int r0 = rg * 2;
  float a0 = 0.f, a1 = 0.f;
#pragma unroll 8
  for (int s = 0; s < 64; s++) {
    float w = sWVb[s * 64 + c];
    a0 += sP[r0 * 320 + h * 80 + s] * w;
    a1 += sP[(r0 + 1) * 320 + h * 80 + s] * w;
  }
#pragma unroll
  for (int tt = 0; tt < 16; tt++) {
    float w = sWf[tt * 64 + c];
    a0 += sP[r0 * 320 + h * 80 + 64 + tt] * w;
    a1 += sP[(r0 + 1) * 320 + h * 80 + 64 + tt] * w;
  }
  const float bv = sb[c];
  const int grow = row0 + r0;
  U[(size_t)grow * 64 + c] = a0 + ats[(size_t)grow * 4 + h] * bv;
  U[(size_t)(grow + 1) * 64 + c] = a1 + ats[(size_t)(grow + 1) * 4 + h] * bv;
}

// ---------------- hV = LN(hV + U @ WO + bO) ----------------
__global__ __launch_bounds__(256) void k_resln(const float* __restrict__ U,
                                               const float* __restrict__ WO,
                                               const float* __restrict__ bO,
                                               const float* __restrict__ g,
                                               const float* __restrict__ bb,
                                               float* __restrict__ hV) {
  __shared__ float sUt[64][16];
  __shared__ float sW[64][64];
  __shared__ float sO[16][64];
  const int t = threadIdx.x;
  const int row0 = blockIdx.x * 16;
#pragma unroll
  for (int q = 0; q < 4; q++) {
    int i = t + 256 * q;
    int r = i >> 6, cc = i & 63;
    sUt[cc][r] = U[(size_t)(row0 + r) * 64 + cc];
  }
#pragma unroll
  for (int q = 0; q < 16; q++) {
    int i = t + 256 * q;
    sW[i >> 6][i & 63] = WO[i];
  }
  __syncthreads();
  const int c = t & 63, rg = t >> 6;
  float acc[4] = {0.f, 0.f, 0.f, 0.f};
#pragma unroll
  for (int s = 0; s < 64; s++) {
    float w = sW[s][c];
    const float4 x = *(const float4*)&sUt[s][rg * 4];
    acc[0] += x.x * w; acc[1] += x.y * w; acc[2] += x.z * w; acc[3] += x.w * w;
  }
  const float bv = bO[c];
#pragma unroll
  for (int u = 0; u < 4; u++) sO[rg * 4 + u][c] = acc[u] + bv;
  __syncthreads();
  const int lane = t & 63, wv = t >> 6;
  const float gv = g[lane], bbv = bb[lane];
  for (int r = wv; r < 16; r += 4) {
    const int row = row0 + r;
    float x = hV[(size_t)row * 64 + lane] + sO[r][lane];
    float s1 = x, s2 = x * x;
#pragma unroll
    for (int off = 32; off; off >>= 1) {
      s1 += __shfl_xor(s1, off, 64);
      s2 += __shfl_xor(s2, off, 64);
    }
    float m = s1 * (1.f / 64.f);
    float var = s2 * (1.f / 64.f) - m * m;
    float inv = rsqrtf(var + 1e-5f);
    hV[(size_t)row * 64 + lane] = (x - m) * inv * gv + bbv;
  }
}

// ---------------- T = relu(hV @ W1 + bf1): 512 blocks x 32 rows ----------------
__global__ __launch_bounds__(256) void k_ffn1(const float* __restrict__ X,
                                              const float* __restrict__ W1,
                                              const float* __restrict__ bf1,
                                              float* __restrict__ T) {
  __shared__ float sXt[64][33];
  __shared__ float sW[32][256];
  const int t = threadIdx.x;
  const int row0 = blockIdx.x * 32;
#pragma unroll
  for (int q = 0; q < 8; q++) {
    int i = t + 256 * q;
    int r = i >> 6, cc = i & 63;
    sXt[cc][r] = X[(size_t)(row0 + r) * 64 + cc];
  }
  float acc[32];
#pragma unroll
  for (int u = 0; u < 32; u++) acc[u] = 0.f;
  for (int kc = 0; kc < 64; kc += 32) {
    __syncthreads();
#pragma unroll
    for (int q = 0; q < 32; q++) {
      int i = t + 256 * q;
      sW[i >> 8][i & 255] = W1[(size_t)(kc + (i >> 8)) * 256 + (i & 255)];
    }
    __syncthreads();
#pragma unroll
    for (int s = 0; s < 32; s++) {
      float w = sW[s][t];
#pragma unroll
      for (int v = 0; v < 8; v++) {
        const float4 x = *(const float4*)&sXt[kc + s][4 * v];
        acc[4 * v + 0] += x.x * w;
        acc[4 * v + 1] += x.y * w;
        acc[4 * v + 2] += x.z * w;
        acc[4 * v + 3] += x.w * w;
      }
    }
  }
  const float bv = bf1[t];
#pragma unroll
  for (int r = 0; r < 32; r++)
    T[(size_t)(row0 + r) * 256 + t] = fmaxf(acc[r] + bv, 0.f);
}

// ---------------- hV = LN(hV + T @ W2 + bf2) * mask: 512 blocks x 32 rows ----------------
__global__ __launch_bounds__(256) void k_ffn2(const float* __restrict__ T,
                                              const float* __restrict__ W2,
                                              const float* __restrict__ bf2,
                                              const float* __restrict__ g,
                                              const float* __restrict__ bb,
                                              const float* __restrict__ mask,
                                              float* __restrict__ hV) {
  __shared__ float sTt[64][33];
  __shared__ float sW[64][64];
  __shared__ float sO[32][64];
  const int t = threadIdx.x;
  const int row0 = blockIdx.x * 32;
  const int c = t & 63, rg = t >> 6;
  float acc[8];
#pragma unroll
  for (int u = 0; u < 8; u++) acc[u] = 0.f;
  for (int kc = 0; kc < 256; kc += 64) {
    __syncthreads();
#pragma unroll
    for (int q = 0; q < 8; q++) {
      int i = t + 256 * q;
      int r = i >> 6, cc = i & 63;
      sTt[cc][r] = T[(size_t)(row0 + r) * 256 + kc + cc];
    }
#pragma unroll
    for (int q = 0; q < 16; q++) {
      int i = t + 256 * q;
      sW[i >> 6][i & 63] = W2[(size_t)(kc + (i >> 6)) * 64 + (i & 63)];
    }
    __syncthreads();
#pragma unroll
    for (int s = 0; s < 64; s++) {
      float w = sW[s][c];
      const float4 x0 = *(const float4*)&sTt[s][rg * 8];
      const float4 x1 = *(const float4*)&sTt[s][rg * 8 + 4];
      acc[0] += x0.x * w; acc[1] += x0.y * w; acc[2] += x0.z * w; acc[3] += x0.w * w;
      acc[4] += x1.x * w; acc[5] += x1.y * w; acc[6] += x1.z * w; acc[7] += x1.w * w;
    }
  }
  const float bv = bf2[c];
#pragma unroll
  for (int u = 0; u < 8; u++) sO[rg * 8 + u][c] = acc[u] + bv;
  __syncthreads();
  const int lane = t & 63, wv = t >> 6;
  const float gv = g[lane], bbv = bb[lane];
  for (int r = wv; r < 32; r += 4) {
    const int row = row0 + r;
    float x = hV[(size_t)row * 64 + lane] + sO[r][lane];
    float s1 = x, s2 = x * x;
#pragma unroll
    for (int off = 32; off; off >>= 1) {
      s1 += __shfl_xor(s1, off, 64);
      s2 += __shfl_xor(s2, off, 64);
    }
    float m = s1 * (1.f / 64.f);
    float var = s2 * (1.f / 64.f) - m * m;
    float inv = rsqrtf(var + 1e-5f);
    float y = (x - m) * inv * gv + bbv;
    hV[(size_t)row * 64 + lane] = y * mask[row];
  }
}

// ---------------- out = hV @ W_out + b_out ----------------
__global__ __launch_bounds__(256) void k_out(const float* __restrict__ hV,
                                             const float* __restrict__ Wo,
                                             const float* __restrict__ bo,
                                             float* __restrict__ out) {
  const int t = threadIdx.x;
  const int lane = t & 63, wv = t >> 6;
  const int row = blockIdx.x * 4 + wv;
  float v = hV[(size_t)row * 64 + lane] * Wo[lane];
#pragma unroll
  for (int off = 32; off; off >>= 1) v += __shfl_xor(v, off, 64);
  if (lane == 0) out[row] = v + bo[0];
}

extern "C" void kernel_launch(void* const* d_in, const int* in_sizes, int n_in,
                              void* d_out, int out_size, void* d_ws, size_t ws_size,
                              hipStream_t stream) {
  const float* coords = (const float*)d_in[0];
  const float* nodef = (const float*)d_in[1];
  const float* mask = (const float*)d_in[2];
  const float* W_node = (const float*)d_in[3];
  const float* b_node = (const float*)d_in[4];
  const float* W_ee = (const float*)d_in[5];
  const float* g_eln = (const float*)d_in[6];
  const float* b_eln = (const float*)d_in[7];
  const float* W_ep = (const float*)d_in[8];
  const float* b_ep = (const float*)d_in[9];
  const float* WQ = (const float*)d_in[10];
  const float* bQ = (const float*)d_in[11];
  const float* WK = (const float*)d_in[12];
  const float* bK = (const float*)d_in[13];
  const float* WV = (const float*)d_in[14];
  const float* bV = (const float*)d_in[15];
  const float* WO = (const float*)d_in[16];
  const float* bO = (const float*)d_in[17];
  const float* g1 = (const float*)d_in[18];
  const float* b1 = (const float*)d_in[19];
  const float* W1 = (const float*)d_in[20];
  const float* bf1 = (const float*)d_in[21];
  const float* W2 = (const float*)d_in[22];
  const float* bf2 = (const float*)d_in[23];
  const float* g2 = (const float*)d_in[24];
  const float* b2 = (const float*)d_in[25];
  const float* W_out = (const float*)d_in[26];
  const float* b_out = (const float*)d_in[27];

  float* ws = (float*)d_ws;
  float* hV = ws;                           // 1,048,576 f
  float* Qb = hV + 1048576;                 // 1,048,576 f  (U)
  float* QWn = Qb + 1048576;                // 4,194,304 f  (alias Tb)
  float* eqw = QWn + 4194304;               // 1,048,576 f
  float* Pg = eqw + 1048576;                // 5,242,880 f  (alias Part)
  float* qb2 = Pg + 5242880;                // 65,536 f
  float* ats = qb2 + 65536;                 // 65,536 f
  int* Eidx = (int*)(ats + 65536);          // 491,520 i
  __half* Eln = (__half*)(Eidx + 491520);   // 7,864,320 h
  float* WKfold = (float*)(Eln + 7864320);  // 4,096 f
  float* bK2 = WKfold + 4096;               // 256 f
  float* WepWV = bK2 + 256;                 // 4,096 f
  float* bV2 = WepWV + 4096;                // 256 f
  float* Tb = QWn;                          // alias: lifetime disjoint
  float* Part = Pg;                         // alias: k_node partials

  k_node_part<<<512, 256, 0, stream>>>(nodef, W_node, Part);
  k_node_sum<<<1024, 256, 0, stream>>>(Part, b_node, hV);
  k_edges<<<16384, 256, 0, stream>>>(coords, mask, W_ee, g_eln, b_eln, Eidx, Eln);
  k_prep<<<8, 256, 0, stream>>>(W_ep, b_ep, WK, bK, WV, bV, WKfold, bK2, WepWV, bV2);
  for (int l = 0; l < 4; l++) {
    k_qproj<<<512, 256, 0, stream>>>(hV, WQ + l * 4096, bQ + l * 64,
                                     WK + l * 8192, WKfold + l * 1024, bK2 + l * 64,
                                     QWn, eqw, qb2);
    k_attn<<<16384, 256, 0, stream>>>(Eln, Eidx, hV, mask, QWn, eqw, qb2, Pg, ats);
    k_upd<<<2048, 256, 0, stream>>>(Pg, ats, WV + l * 8192, WepWV + l * 1024,
                                    bV2 + l * 64, Qb);
    k_resln<<<1024, 256, 0, stream>>>(Qb, WO + l * 4096, bO + l * 64,
                                      g1 + l * 64, b1 + l * 64, hV);
    k_ffn1<<<512, 256, 0, stream>>>(hV, W1 + l * 16384, bf1 + l * 256, Tb);
    k_ffn2<<<512, 256, 0, stream>>>(Tb, W2 + l * 16384, bf2 + l * 64,
                                    g2 + l * 64, b2 + l * 64, mask, hV);
  }
  k_out<<<4096, 256, 0, stream>>>(hV, W_out, b_out, (float*)d_out);
}

// Round 13
// 793.486 us; speedup vs baseline: 1.0110x; 1.0110x over previous
//
#include <hip/hip_runtime.h>
#include <hip/hip_fp16.h>

#define L_ 2048
#define NROW 16384
#define FIN 1038

// ---------------- node embedding part: Part[split] = X[:, ks:ke] @ W[ks:ke, :] ----------------
__global__ __launch_bounds__(256) void k_node_part(const float* __restrict__ X,
                                                   const float* __restrict__ W,
                                                   float* __restrict__ Part) {
  const int rb = blockIdx.x >> 2;
  const int split = blockIdx.x & 3;
  const int kStart = split * 260;
  const int kEnd = (split == 3) ? FIN : (kStart + 260);
  const int t = threadIdx.x;
  const int row0 = rb * 128;
  __shared__ float Xs[2][16][132];
  __shared__ float Ws[2][16][64];
  const int ri = t >> 3;
  const int ci = t & 7;
  const int sxr = t >> 2;
  const int sxk = (t & 3) * 4;
  const int swr = t >> 4;
  const int swc = (t & 15) * 4;

  float acc[4][8];
#pragma unroll
  for (int u = 0; u < 4; u++)
#pragma unroll
    for (int v = 0; v < 8; v++) acc[u][v] = 0.f;

  float4 px0, px1, pwv;

#define LOADX(dst, kc, rsub)                                            \
  {                                                                     \
    const int col = (kc) + sxk;                                         \
    const float* xr = &X[(size_t)(row0 + sxr + 64 * (rsub)) * FIN];     \
    float4 v = make_float4(0.f, 0.f, 0.f, 0.f);                         \
    if (col + 4 <= kEnd) v = *(const float4*)&xr[col];                  \
    else {                                                              \
      if (col + 0 < kEnd) v.x = xr[col + 0];                            \
      if (col + 1 < kEnd) v.y = xr[col + 1];                            \
      if (col + 2 < kEnd) v.z = xr[col + 2];                            \
      if (col + 3 < kEnd) v.w = xr[col + 3];                            \
    }                                                                   \
    dst = v;                                                            \
  }
#define LOADW(dst, kc)                                                  \
  {                                                                     \
    const int j = (kc) + swr;                                           \
    dst = (j < kEnd) ? *(const float4*)&W[(size_t)j * 64 + swc]         \
                     : make_float4(0.f, 0.f, 0.f, 0.f);                 \
  }

  LOADX(px0, kStart, 0);
  LOADX(px1, kStart, 1);
  LOADW(pwv, kStart);

  int buf = 0;
  for (int kc = kStart; kc < kEnd; kc += 16) {
    Xs[buf][sxk + 0][sxr] = px0.x;
    Xs[buf][sxk + 1][sxr] = px0.y;
    Xs[buf][sxk + 2][sxr] = px0.z;
    Xs[buf][sxk + 3][sxr] = px0.w;
    Xs[buf][sxk + 0][64 + sxr] = px1.x;
    Xs[buf][sxk + 1][64 + sxr] = px1.y;
    Xs[buf][sxk + 2][64 + sxr] = px1.z;
    Xs[buf][sxk + 3][64 + sxr] = px1.w;
    *(float4*)&Ws[buf][swr][swc] = pwv;
    __syncthreads();
    const int kn = kc + 16;
    if (kn < kEnd) {
      LOADX(px0, kn, 0);
      LOADX(px1, kn, 1);
      LOADW(pwv, kn);
    }
#pragma unroll
    for (int k = 0; k < 16; k++) {
      const float4 xv = *(const float4*)&Xs[buf][k][4 * ri];
      const float4 w0 = *(const float4*)&Ws[buf][k][8 * ci];
      const float4 w1 = *(const float4*)&Ws[buf][k][8 * ci + 4];
      const float xr_[4] = {xv.x, xv.y, xv.z, xv.w};
      const float wc_[8] = {w0.x, w0.y, w0.z, w0.w, w1.x, w1.y, w1.z, w1.w};
#pragma unroll
      for (int u = 0; u < 4; u++)
#pragma unroll
        for (int v = 0; v < 8; v++) acc[u][v] += xr_[u] * wc_[v];
    }
    buf ^= 1;
  }
#undef LOADX
#undef LOADW

  float* P = Part + (size_t)split * (NROW * 64);
#pragma unroll
  for (int u = 0; u < 4; u++) {
    const int row = row0 + 4 * ri + u;
    *(float4*)&P[(size_t)row * 64 + 8 * ci] =
        make_float4(acc[u][0], acc[u][1], acc[u][2], acc[u][3]);
    *(float4*)&P[(size_t)row * 64 + 8 * ci + 4] =
        make_float4(acc[u][4], acc[u][5], acc[u][6], acc[u][7]);
  }
}

// ---------------- hV = sum of 4 partials + bias ----------------
__global__ __launch_bounds__(256) void k_node_sum(const float* __restrict__ Part,
                                                  const float* __restrict__ bias,
                                                  float* __restrict__ out) {
  const int i = (blockIdx.x * 256 + threadIdx.x) * 4;
  const float4 a = *(const float4*)&Part[i];
  const float4 b = *(const float4*)&Part[1048576 + i];
  const float4 c = *(const float4*)&Part[2 * 1048576 + i];
  const float4 d = *(const float4*)&Part[3 * 1048576 + i];
  const float4 bb = *(const float4*)&bias[i & 63];
  float4 o;
  o.x = a.x + b.x + c.x + d.x + bb.x;
  o.y = a.y + b.y + c.y + d.y + bb.y;
  o.z = a.z + b.z + c.z + d.z + bb.z;
  o.w = a.w + b.w + c.w + d.w + bb.w;
  *(float4*)&out[i] = o;
}

// ---------------- edges: distances + histogram-select top-30 + E_ln precompute (R9 proven) ----------------
__global__ __launch_bounds__(256) void k_edges(const float* __restrict__ coords,
                                               const float* __restrict__ mask,
                                               const float* __restrict__ Wee,
                                               const float* __restrict__ geln,
                                               const float* __restrict__ beln,
                                               int* __restrict__ Eidx,
                                               __half* __restrict__ Eln) {
  const int row = blockIdx.x;
  const int b = row >> 11;
  const int t = threadIdx.x;
  const int lane = t & 63, wid = t >> 6;
  __shared__ float sredf[4];
  __shared__ unsigned int hist[2048];
  __shared__ unsigned int wtot[4];
  __shared__ int s_bin, s_need;
  __shared__ int s_lcnt, s_outcnt;
  __shared__ unsigned int s_lkey[64];
  __shared__ int s_lidx[64];
  __shared__ int s_sel[64];
  __shared__ float sD[30];
  __shared__ int sJ[30];
  __shared__ float sWee[16][16];
  __shared__ float sg[16], sb[16];
  __shared__ float sRBF[30][16];

  if (t < 256) sWee[t >> 4][t & 15] = Wee[t];
  if (t < 16) { sg[t] = geln[t]; sb[t] = beln[t]; }
  if (t == 0) { s_lcnt = 0; s_outcnt = 0; }

  const float* cb = coords + (size_t)b * (L_ * 3);
  const int i = row & (L_ - 1);
  const float cix = cb[i * 3 + 0], ciy = cb[i * 3 + 1], ciz = cb[i * 3 + 2];
  const float mi = mask[row];
  const float* mb = mask + (size_t)b * L_;
  float d[8], mj[8];
  float dmax = 0.f;
#pragma unroll
  for (int u = 0; u < 8; u++) {
    int j = t + 256 * u;
    float dx = cix - cb[j * 3 + 0];
    float dy = ciy - cb[j * 3 + 1];
    float dz = ciz - cb[j * 3 + 2];
    float dist = sqrtf(dx * dx + dy * dy + dz * dz + 1e-6f);
    d[u] = dist;
    mj[u] = mb[j];
    dmax = fmaxf(dmax, dist);
  }
#pragma unroll
  for (int off = 32; off; off >>= 1) dmax = fmaxf(dmax, __shfl_xor(dmax, off, 64));
  if (lane == 0) sredf[wid] = dmax;
#pragma unroll
  for (int q = 0; q < 8; q++) hist[t * 8 + q] = 0u;
  __syncthreads();
  dmax = fmaxf(fmaxf(sredf[0], sredf[1]), fmaxf(sredf[2], sredf[3]));
  const float scale = 1024.0f / fmaxf(dmax, 1e-20f);
  float adj[8];
  int bin[8];
#pragma unroll
  for (int u = 0; u < 8; u++) {
    adj[u] = d[u] + (1.f - mi * mj[u]) * dmax;
    int bi = (int)(adj[u] * scale);
    bin[u] = bi < 2047 ? bi : 2047;
    atomicAdd(&hist[bin[u]], 1u);
  }
  __syncthreads();
  unsigned int c[8];
  unsigned int local = 0;
#pragma unroll
  for (int q = 0; q < 8; q++) { c[q] = hist[t * 8 + q]; local += c[q]; }
  unsigned int incl = local;
#pragma unroll
  for (int off = 1; off < 64; off <<= 1) {
    unsigned int v = __shfl_up(incl, off, 64);
    if (lane >= off) incl += v;
  }
  if (lane == 63) wtot[wid] = incl;
  __syncthreads();
  unsigned int excl = incl - local;
  for (int w = 0; w < wid; w++) excl += wtot[w];
  if (excl < 30u && excl + local >= 30u) {
    unsigned int run = excl;
#pragma unroll
    for (int q = 0; q < 8; q++) {
      if (run + c[q] >= 30u) { s_bin = t * 8 + q; s_need = 30 - (int)run; break; }
      run += c[q];
    }
  }
  __syncthreads();
  const int tbin = s_bin;
  int pos[8];
#pragma unroll
  for (int u = 0; u < 8; u++) {
    pos[u] = -1;
    if (bin[u] == tbin) {
      int p = atomicAdd(&s_lcnt, 1);
      if (p < 64) { s_lkey[p] = __float_as_uint(adj[u]); s_lidx[p] = t + 256 * u; pos[u] = p; }
    }
  }
  __syncthreads();
  {
    int n = s_lcnt < 64 ? s_lcnt : 64;
    if (t < n) {
      unsigned int k0 = s_lkey[t];
      int j0 = s_lidx[t];
      int r = 0;
      for (int m = 0; m < n; m++) {
        unsigned int km = s_lkey[m];
        r += (km < k0) || (km == k0 && s_lidx[m] < j0);
      }
      s_sel[t] = (r < s_need) ? 1 : 0;
    }
  }
  __syncthreads();
#pragma unroll
  for (int u = 0; u < 8; u++) {
    bool sel = (bin[u] < tbin) || (pos[u] >= 0 && s_sel[pos[u]]);
    if (sel) {
      int o = atomicAdd(&s_outcnt, 1);
      if (o < 30) { sJ[o] = t + 256 * u; sD[o] = adj[u]; }
    }
  }
  __syncthreads();
  if (t < 30) Eidx[(size_t)row * 30 + t] = sJ[t];
  for (int o = t; o < 480; o += 256) {
    int k = o >> 4, s = o & 15;
    float mu = 2.0f + (4.0f / 3.0f) * (float)s;
    float z = (sD[k] - mu) * 0.8f;
    sRBF[k][s] = __expf(-z * z);
  }
  __syncthreads();
  if (t < 240) {
    int k = t >> 3, p = t & 7;
    int c0 = p * 2, c1 = c0 + 1;
    float e0 = 0.f, e1 = 0.f;
#pragma unroll
    for (int s = 0; s < 16; s++) {
      float r = sRBF[k][s];
      e0 += r * sWee[s][c0];
      e1 += r * sWee[s][c1];
    }
    float s1 = e0 + e1, s2 = e0 * e0 + e1 * e1;
#pragma unroll
    for (int m = 1; m < 8; m <<= 1) {
      s1 += __shfl_xor(s1, m, 64);
      s2 += __shfl_xor(s2, m, 64);
    }
    float mean = s1 * (1.f / 16.f);
    float var = s2 * (1.f / 16.f) - mean * mean;
    float inv = rsqrtf(var + 1e-5f);
    Eln[(size_t)row * 480 + k * 16 + c0] = __float2half((e0 - mean) * inv * sg[c0] + sb[c0]);
    Eln[(size_t)row * 480 + k * 16 + c1] = __float2half((e1 - mean) * inv * sg[c1] + sb[c1]);
  }
}

// ---------------- per-layer weight folding ----------------
__global__ __launch_bounds__(256) void k_prep(const float* __restrict__ Wep,
                                              const float* __restrict__ bep,
                                              const float* __restrict__ WK,
                                              const float* __restrict__ bK,
                                              const float* __restrict__ WV,
                                              const float* __restrict__ bV,
                                              float* __restrict__ WKfold,
                                              float* __restrict__ bK2,
                                              float* __restrict__ WepWV,
                                              float* __restrict__ bV2) {
  const int l = blockIdx.x >> 1, isV = blockIdx.x & 1;
  const float* W = (isV ? WV : WK) + (size_t)l * 8192;
  const float* bsrc = (isV ? bV : bK) + l * 64;
  float* fold = (isV ? WepWV : WKfold) + l * 1024;
  float* b2 = (isV ? bV2 : bK2) + l * 64;
  __shared__ float sW[64][64];
  __shared__ float sWep[16][64];
  const int t = threadIdx.x;
  for (int q = 0; q < 16; q++) { int i = t + 256 * q; sW[i >> 6][i & 63] = W[i]; }
  for (int q = 0; q < 4; q++)  { int i = t + 256 * q; sWep[i >> 6][i & 63] = Wep[i]; }
  __syncthreads();
  const int c = t & 63, rg = t >> 6;
  for (int r = rg; r < 16; r += 4) {
    float a = 0.f;
    for (int s = 0; s < 64; s++) a += sWep[r][s] * sW[s][c];
    fold[r * 64 + c] = a;
  }
  if (t < 64) {
    float a = bsrc[t];
    for (int s = 0; s < 64; s++) a += bep[s] * sW[s][t];
    b2[t] = a;
  }
}

// ---------------- k_qproj: fused Q=hV@WQ+bQ (LDS) -> QWn/eqw/qb2; 512 blocks x 32 rows ----------------
__global__ __launch_bounds__(256) void k_qproj(const float* __restrict__ hV,
                                               const float* __restrict__ WQ,
                                               const float* __restrict__ bQ,
                                               const float* __restrict__ WK,
                                               const float* __restrict__ WKfold,
                                               const float* __restrict__ bK2,
                                               float* __restrict__ QWn,
                                               float* __restrict__ eqw,
                                               float* __restrict__ qb2) {
  __shared__ float sX[32 * 68];
  __shared__ float sW[64 * 64];  // phase 1: WQ row-major; reused after barrier as sQ[32*68]
  __shared__ float sb[64];
  const int t = threadIdx.x;
  const int row0 = blockIdx.x * 32;
  const int c = t & 63, rg = t >> 6;
  const int h = t >> 6, s2 = t & 63;
  const float4 wk0 = *(const float4*)&WK[(size_t)(64 + s2) * 64 + h * 16 + 0];
  const float4 wk1 = *(const float4*)&WK[(size_t)(64 + s2) * 64 + h * 16 + 4];
  const float4 wk2 = *(const float4*)&WK[(size_t)(64 + s2) * 64 + h * 16 + 8];
  const float4 wk3 = *(const float4*)&WK[(size_t)(64 + s2) * 64 + h * 16 + 12];
  const int rb4 = (t >> 4) & 3, tt = t & 15;
  const float4 wf0 = *(const float4*)&WKfold[tt * 64 + h * 16 + 0];
  const float4 wf1 = *(const float4*)&WKfold[tt * 64 + h * 16 + 4];
  const float4 wf2 = *(const float4*)&WKfold[tt * 64 + h * 16 + 8];
  const float4 wf3 = *(const float4*)&WKfold[tt * 64 + h * 16 + 12];
#pragma unroll
  for (int q = 0; q < 8; q++) {
    int i = t + 256 * q;
    sX[(i >> 6) * 68 + (i & 63)] = hV[(size_t)(row0 + (i >> 6)) * 64 + (i & 63)];
  }
#pragma unroll
  for (int q = 0; q < 16; q++) {
    int i = t + 256 * q;
    sW[i] = WQ[i];
  }
  if (t < 64) sb[t] = bK2[t];
  __syncthreads();
  float acc[8];
#pragma unroll
  for (int u = 0; u < 8; u++) acc[u] = 0.f;
#pragma unroll
  for (int s0 = 0; s0 < 64; s0 += 4) {
    float w0 = sW[s0 * 64 + c], w1 = sW[(s0 + 1) * 64 + c];
    float w2 = sW[(s0 + 2) * 64 + c], w3 = sW[(s0 + 3) * 64 + c];
#pragma unroll
    for (int u = 0; u < 8; u++) {
      const float4 a = *(const float4*)&sX[(rg + 4 * u) * 68 + s0];
      acc[u] += a.x * w0 + a.y * w1 + a.z * w2 + a.w * w3;
    }
  }
  __syncthreads();
  const float bb = bQ[c];
  float* sQ = sW;
#pragma unroll
  for (int u = 0; u < 8; u++) sQ[(rg + 4 * u) * 68 + c] = acc[u] + bb;
  __syncthreads();
  for (int r = 0; r < 32; r++) {
    const float4 q0 = *(const float4*)&sQ[r * 68 + h * 16 + 0];
    const float4 q1 = *(const float4*)&sQ[r * 68 + h * 16 + 4];
    const float4 q2 = *(const float4*)&sQ[r * 68 + h * 16 + 8];
    const float4 q3 = *(const float4*)&sQ[r * 68 + h * 16 + 12];
    float a = q0.x * wk0.x + q0.y * wk0.y + q0.z * wk0.z + q0.w * wk0.w
            + q1.x * wk1.x + q1.y * wk1.y + q1.z * wk1.z + q1.w * wk1.w
            + q2.x * wk2.x + q2.y * wk2.y + q2.z * wk2.z + q2.w * wk2.w
            + q3.x * wk3.x + q3.y * wk3.y + q3.z * wk3.z + q3.w * wk3.w;
    QWn[(size_t)(row0 + r) * 256 + h * 64 + s2] = a;
  }
  for (int rr = 0; rr < 8; rr++) {
    const int r = rr * 4 + rb4;
    const float4 q0 = *(const float4*)&sQ[r * 68 + h * 16 + 0];
    const float4 q1 = *(const float4*)&sQ[r * 68 + h * 16 + 4];
    const float4 q2 = *(const float4*)&sQ[r * 68 + h * 16 + 8];
    const float4 q3 = *(const float4*)&sQ[r * 68 + h * 16 + 12];
    float a = q0.x * wf0.x + q0.y * wf0.y + q0.z * wf0.z + q0.w * wf0.w
            + q1.x * wf1.x + q1.y * wf1.y + q1.z * wf1.z + q1.w * wf1.w
            + q2.x * wf2.x + q2.y * wf2.y + q2.z * wf2.z + q2.w * wf2.w
            + q3.x * wf3.x + q3.y * wf3.y + q3.z * wf3.z + q3.w * wf3.w;
    eqw[(size_t)(row0 + r) * 64 + h * 16 + tt] = a;
  }
  if (t < 128) {
    const int r = t >> 2, h2 = t & 3;
    float a = 0.f;
#pragma unroll
    for (int d = 0; d < 16; d++) a += sQ[r * 68 + h2 * 16 + d] * sb[h2 * 16 + d];
    qb2[(size_t)(row0 + r) * 4 + h2] = a;
  }
}

// ---------------- k_attn v3: split-k P-phase + vectorized global staging ----------------
__global__ __launch_bounds__(256) void k_attn(
    const __half* __restrict__ Eln, const int* __restrict__ Eidx,
    const float* __restrict__ hV, const float* __restrict__ mask,
    const float* __restrict__ QWn, const float* __restrict__ eqw,
    const float* __restrict__ qb2,
    float* __restrict__ Pg, float* __restrict__ attsum) {
  const int row = blockIdx.x;
  const int b = row >> 11;
  const int t = threadIdx.x;
  const int lane = t & 63, wid = t >> 6;
  __shared__ float sHV[30 * 65];
  __shared__ float sE[30 * 17];
  __shared__ float sQn[256];
  __shared__ float swq[64];
  __shared__ float sqb2[4];
  __shared__ float smk[32];
  __shared__ float satt4[32 * 4];
  __shared__ float sPc[4][4][64];
  __shared__ float sEc[4][4][16];

  sQn[t] = QWn[(size_t)row * 256 + t];
  if (t < 64) swq[t] = eqw[(size_t)row * 64 + t];
  if (t < 4) sqb2[t] = qb2[(size_t)row * 4 + t];
  if (t < 30) smk[t] = mask[(b << 11) + Eidx[(size_t)row * 30 + t]] * mask[row];
  if (t < 240) {
    const __half2 h2v = *(const __half2*)&Eln[(size_t)row * 480 + 2 * t];
    const float2 f2 = __half22float2(h2v);
    const int k = (2 * t) >> 4, c = (2 * t) & 15;
    sE[k * 17 + c] = f2.x;
    sE[k * 17 + c + 1] = f2.y;
  }
#pragma unroll
  for (int q = 0; q < 4; q++) {
    int o = t + 256 * q;
    if (o < 960) {
      const int k = o >> 5, c2 = (o & 31) * 2;
      const int j = Eidx[(size_t)row * 30 + k];
      const float2 v = *(const float2*)&hV[((size_t)(b << 11) + j) * 64 + c2];
      sHV[k * 65 + c2] = v.x;
      sHV[k * 65 + c2 + 1] = v.y;
    }
  }
  __syncthreads();

  const int kk = (lane < 30) ? lane : (lane - 30);
  const int sbase = (lane < 30) ? 0 : 32;
  const int tbase = (lane < 30) ? 0 : 8;
  float lg = 0.f;
  if (lane < 60) {
#pragma unroll
    for (int s = 0; s < 32; s++)
      lg += sHV[kk * 65 + sbase + s] * sQn[wid * 64 + sbase + s];
#pragma unroll
    for (int tt = 0; tt < 8; tt++)
      lg += sE[kk * 17 + tbase + tt] * swq[wid * 16 + tbase + tt];
  }
  float oth = __shfl(lg, lane + 30, 64);
  float mk = (lane < 30) ? smk[lane] : 0.f;
  float lgv = (lane < 30 && mk > 0.f) ? (lg + oth + sqb2[wid]) * 0.25f
                                      : -3.402823466e38f;
  float mx = lgv;
#pragma unroll
  for (int off = 16; off; off >>= 1) mx = fmaxf(mx, __shfl_xor(mx, off, 64));
  float e = (lane < 30) ? __expf(lgv - mx) : 0.f;
  float den = e;
#pragma unroll
  for (int off = 16; off; off >>= 1) den += __shfl_xor(den, off, 64);
  float att = e * (1.f / den) * mk;
  float ss = att;
#pragma unroll
  for (int off = 16; off; off >>= 1) ss += __shfl_xor(ss, off, 64);
  if (lane == 0) attsum[(size_t)row * 4 + wid] = ss;
  if (lane < 30) satt4[lane * 4 + wid] = att;
  __syncthreads();

  const int k0 = wid * 8;
  const int knum = (wid == 3) ? 6 : 8;
  float pn0 = 0.f, pn1 = 0.f, pn2 = 0.f, pn3 = 0.f;
  float ea0 = 0.f, ea1 = 0.f, ea2 = 0.f, ea3 = 0.f;
  for (int u = 0; u < knum; u++) {
    const int k2 = k0 + u;
    const float4 a4 = *(const float4*)&satt4[k2 * 4];
    const float hvv = sHV[k2 * 65 + lane];
    pn0 += a4.x * hvv; pn1 += a4.y * hvv; pn2 += a4.z * hvv; pn3 += a4.w * hvv;
    const float ev = (lane < 16) ? sE[k2 * 17 + lane] : 0.f;
    ea0 += a4.x * ev; ea1 += a4.y * ev; ea2 += a4.z * ev; ea3 += a4.w * ev;
  }
  sPc[wid][0][lane] = pn0;
  sPc[wid][1][lane] = pn1;
  sPc[wid][2][lane] = pn2;
  sPc[wid][3][lane] = pn3;
  if (lane < 16) {
    sEc[wid][0][lane] = ea0;
    sEc[wid][1][lane] = ea1;
    sEc[wid][2][lane] = ea2;
    sEc[wid][3][lane] = ea3;
  }
  __syncthreads();
  float pv = sPc[0][wid][lane] + sPc[1][wid][lane] + sPc[2][wid][lane] + sPc[3][wid][lane];
  float* pr = Pg + (size_t)row * 320 + wid * 80;
  pr[lane] = pv;
  if (lane < 16) {
    float ev2 = sEc[0][wid][lane] + sEc[1][wid][lane] + sEc[2][wid][lane] + sEc[3][wid][lane];
    pr[64 + lane] = ev2;
  }
}

// ---------------- upd = Pnode @ WV_bot + eatt @ WepWV + ats*bV2 ----------------
__global__ __launch_bounds__(256) void k_upd(const float* __restrict__ Pg,
                                             const float* __restrict__ ats,
                                             const float* __restrict__ WV,
                                             const float* __restrict__ WepWV,
                                             const float* __restrict__ bV2,
                                             float* __restrict__ U) {
  __shared__ float sWVb[64 * 64];
  __shared__ float sWf[16 * 64];
  __shared__ float sb[64];
  __shared__ float sP[8 * 320];
  const int t = threadIdx.x;
  const int row0 = blockIdx.x * 8;
  for (int q = 0; q < 16; q++) {
    int i = t + 256 * q;
    sWVb[i] = WV[4096 + i];
  }
  for (int q = 0; q < 4; q++) {
    int i = t + 256 * q;
    sWf[i] = WepWV[i];
  }
  if (t < 64) sb[t] = bV2[t];
  for (int q = 0; q < 10; q++) {
    int i = t + 256 * q;
    sP[i] = Pg[(size_t)row0 * 320 + i];
  }
  __syncthreads();
  const int c = t & 63, rg = t >> 6;
  const int h = c >> 4;
  const int r0 = rg * 2;
  float a0 = 0.f, a1 = 0.f;
#pragma unroll 8
  for (int s = 0; s < 64; s++) {
    float w = sWVb[s * 64 + c];
    a0 += sP[r0 * 320 + h * 80 + s] * w;
    a1 += sP[(r0 + 1) * 320 + h * 80 + s] * w;
  }
#pragma unroll
  for (int tt = 0; tt < 16; tt++) {
    float w = sWf[tt * 64 + c];
    a0 += sP[r0 * 320 + h * 80 + 64 + tt] * w;
    a1 += sP[(r0 + 1) * 320 + h * 80 + 64 + tt] * w;
  }
  const float bv = sb[c];
  const int grow = row0 + r0;
  U[(size_t)grow * 64 + c] = a0 + ats[(size_t)grow * 4 + h] * bv;
  U[(size_t)(grow + 1) * 64 + c] = a1 + ats[(size_t)(grow + 1) * 4 + h] * bv;
}

// ---------------- hV = LN(hV + U @ WO + bO) ----------------
__global__ __launch_bounds__(256) void k_resln(const float* __restrict__ U,
                                               const float* __restrict__ WO,
                                               const float* __restrict__ bO,
                                               const float* __restrict__ g,
                                               const float* __restrict__ bb,
                                               float* __restrict__ hV) {
  __shared__ float sUt[64][16];
  __shared__ float sW[64][64];
  __shared__ float sO[16][64];
  const int t = threadIdx.x;
  const int row0 = blockIdx.x * 16;
#pragma unroll
  for (int q = 0; q < 4; q++) {
    int i = t + 256 * q;
    int r = i >> 6, cc = i & 63;
    sUt[cc][r] = U[(size_t)(row0 + r) * 64 + cc];
  }
#pragma unroll
  for (int q = 0; q < 16; q++) {
    int i = t + 256 * q;
    sW[i >> 6][i & 63] = WO[i];
  }
  __syncthreads();
  const int c = t & 63, rg = t >> 6;
  float acc[4] = {0.f, 0.f, 0.f, 0.f};
#pragma unroll
  for (int s = 0; s < 64; s++) {
    float w = sW[s][c];
    const float4 x = *(const float4*)&sUt[s][rg * 4];
    acc[0] += x.x * w; acc[1] += x.y * w; acc[2] += x.z * w; acc[3] += x.w * w;
  }
  const float bv = bO[c];
#pragma unroll
  for (int u = 0; u < 4; u++) sO[rg * 4 + u][c] = acc[u] + bv;
  __syncthreads();
  const int lane = t & 63, wv = t >> 6;
  const float gv = g[lane], bbv = bb[lane];
  for (int r = wv; r < 16; r += 4) {
    const int row = row0 + r;
    float x = hV[(size_t)row * 64 + lane] + sO[r][lane];
    float s1 = x, s2 = x * x;
#pragma unroll
    for (int off = 32; off; off >>= 1) {
      s1 += __shfl_xor(s1, off, 64);
      s2 += __shfl_xor(s2, off, 64);
    }
    float m = s1 * (1.f / 64.f);
    float var = s2 * (1.f / 64.f) - m * m;
    float inv = rsqrtf(var + 1e-5f);
    hV[(size_t)row * 64 + lane] = (x - m) * inv * gv + bbv;
  }
}

// ---------------- T = relu(hV @ W1 + bf1) ----------------
__global__ __launch_bounds__(256) void k_ffn1(const float* __restrict__ X,
                                              const float* __restrict__ W1,
                                              const float* __restrict__ bf1,
                                              float* __restrict__ T) {
  __shared__ float sXt[64][16];
  __shared__ float sW[32][256];
  const int t = threadIdx.x;
  const int row0 = blockIdx.x * 16;
#pragma unroll
  for (int q = 0; q < 4; q++) {
    int i = t + 256 * q;
    int r = i >> 6, cc = i & 63;
    sXt[cc][r] = X[(size_t)(row0 + r) * 64 + cc];
  }
  float acc[16];
#pragma unroll
  for (int u = 0; u < 16; u++) acc[u] = 0.f;
  for (int kc = 0; kc < 64; kc += 32) {
    __syncthreads();
#pragma unroll
    for (int q = 0; q < 32; q++) {
      int i = t + 256 * q;
      sW[i >> 8][i & 255] = W1[(size_t)(kc + (i >> 8)) * 256 + (i & 255)];
    }
    __syncthreads();
#pragma unroll
    for (int s = 0; s < 32; s++) {
      float w = sW[s][t];
      const float4 x0 = *(const float4*)&sXt[kc + s][0];
      const float4 x1 = *(const float4*)&sXt[kc + s][4];
      const float4 x2 = *(const float4*)&sXt[kc + s][8];
      const float4 x3 = *(const float4*)&sXt[kc + s][12];
      acc[0] += x0.x * w; acc[1] += x0.y * w; acc[2] += x0.z * w; acc[3] += x0.w * w;
      acc[4] += x1.x * w; acc[5] += x1.y * w; acc[6] += x1.z * w; acc[7] += x1.w * w;
      acc[8] += x2.x * w; acc[9] += x2.y * w; acc[10] += x2.z * w; acc[11] += x2.w * w;
      acc[12] += x3.x * w; acc[13] += x3.y * w; acc[14] += x3.z * w; acc[15] += x3.w * w;
    }
  }
  const float bv = bf1[t];
#pragma unroll
  for (int r = 0; r < 16; r++)
    T[(size_t)(row0 + r) * 256 + t] = fmaxf(acc[r] + bv, 0.f);
}

// ---------------- hV = LN(hV + T @ W2 + bf2) * mask ----------------
__global__ __launch_bounds__(256) void k_ffn2(const float* __restrict__ T,
                                              const float* __restrict__ W2,
                                              const float* __restrict__ bf2,
                                              const float* __restrict__ g,
                                              const float* __restrict__ bb,
                                              const float* __restrict__ mask,
                                              float* __restrict__ hV) {
  __shared__ float sTt[64][16];
  __shared__ float sW[64][64];
  __shared__ float sO[16][64];
  const int t = threadIdx.x;
  const int row0 = blockIdx.x * 16;
  const int c = t & 63, rg = t >> 6;
  float acc[4] = {0.f, 0.f, 0.f, 0.f};
  for (int kc = 0; kc < 256; kc += 64) {
    __syncthreads();
#pragma unroll
    for (int q = 0; q < 4; q++) {
      int i = t + 256 * q;
      int r = i >> 6, cc = i & 63;
      sTt[cc][r] = T[(size_t)(row0 + r) * 256 + kc + cc];
    }
#pragma unroll
    for (int q = 0; q < 16; q++) {
      int i = t + 256 * q;
      sW[i >> 6][i & 63] = W2[(size_t)(kc + (i >> 6)) * 64 + (i & 63)];
    }
    __syncthreads();
#pragma unroll
    for (int s = 0; s < 64; s++) {
      float w = sW[s][c];
      const float4 x = *(const float4*)&sTt[s][rg * 4];
      acc[0] += x.x * w; acc[1] += x.y * w; acc[2] += x.z * w; acc[3] += x.w * w;
    }
  }
  const float bv = bf2[c];
#pragma unroll
  for (int u = 0; u < 4; u++) sO[rg * 4 + u][c] = acc[u] + bv;
  __syncthreads();
  const int lane = t & 63, wv = t >> 6;
  const float gv = g[lane], bbv = bb[lane];
  for (int r = wv; r < 16; r += 4) {
    const int row = row0 + r;
    float x = hV[(size_t)row * 64 + lane] + sO[r][lane];
    float s1 = x, s2 = x * x;
#pragma unroll
    for (int off = 32; off; off >>= 1) {
      s1 += __shfl_xor(s1, off, 64);
      s2 += __shfl_xor(s2, off, 64);
    }
    float m = s1 * (1.f / 64.f);
    float var = s2 * (1.f / 64.f) - m * m;
    float inv = rsqrtf(var + 1e-5f);
    float y = (x - m) * inv * gv + bbv;
    hV[(size_t)row * 64 + lane] = y * mask[row];
  }
}

// ---------------- out = hV @ W_out + b_out ----------------
__global__ __launch_bounds__(256) void k_out(const float* __restrict__ hV,
                                             const float* __restrict__ Wo,
                                             const float* __restrict__ bo,
                                             float* __restrict__ out) {
  const int t = threadIdx.x;
  const int lane = t & 63, wv = t >> 6;
  const int row = blockIdx.x * 4 + wv;
  float v = hV[(size_t)row * 64 + lane] * Wo[lane];
#pragma unroll
  for (int off = 32; off; off >>= 1) v += __shfl_xor(v, off, 64);
  if (lane == 0) out[row] = v + bo[0];
}

extern "C" void kernel_launch(void* const* d_in, const int* in_sizes, int n_in,
                              void* d_out, int out_size, void* d_ws, size_t ws_size,
                              hipStream_t stream) {
  const float* coords = (const float*)d_in[0];
  const float* nodef = (const float*)d_in[1];
  const float* mask = (const float*)d_in[2];
  const float* W_node = (const float*)d_in[3];
  const float* b_node = (const float*)d_in[4];
  const float* W_ee = (const float*)d_in[5];
  const float* g_eln = (const float*)d_in[6];
  const float* b_eln = (const float*)d_in[7];
  const float* W_ep = (const float*)d_in[8];
  const float* b_ep = (const float*)d_in[9];
  const float* WQ = (const float*)d_in[10];
  const float* bQ = (const float*)d_in[11];
  const float* WK = (const float*)d_in[12];
  const float* bK = (const float*)d_in[13];
  const float* WV = (const float*)d_in[14];
  const float* bV = (const float*)d_in[15];
  const float* WO = (const float*)d_in[16];
  const float* bO = (const float*)d_in[17];
  const float* g1 = (const float*)d_in[18];
  const float* b1 = (const float*)d_in[19];
  const float* W1 = (const float*)d_in[20];
  const float* bf1 = (const float*)d_in[21];
  const float* W2 = (const float*)d_in[22];
  const float* bf2 = (const float*)d_in[23];
  const float* g2 = (const float*)d_in[24];
  const float* b2 = (const float*)d_in[25];
  const float* W_out = (const float*)d_in[26];
  const float* b_out = (const float*)d_in[27];

  float* ws = (float*)d_ws;
  float* hV = ws;                           // 1,048,576 f
  float* Qb = hV + 1048576;                 // 1,048,576 f  (U)
  float* QWn = Qb + 1048576;                // 4,194,304 f  (alias Tb)
  float* eqw = QWn + 4194304;               // 1,048,576 f
  float* Pg = eqw + 1048576;                // 5,242,880 f  (alias Part)
  float* qb2 = Pg + 5242880;                // 65,536 f
  float* ats = qb2 + 65536;                 // 65,536 f
  int* Eidx = (int*)(ats + 65536);          // 491,520 i
  __half* Eln = (__half*)(Eidx + 491520);   // 7,864,320 h
  float* WKfold = (float*)(Eln + 7864320);  // 4,096 f
  float* bK2 = WKfold + 4096;               // 256 f
  float* WepWV = bK2 + 256;                 // 4,096 f
  float* bV2 = WepWV + 4096;                // 256 f
  float* Tb = QWn;                          // alias: lifetime disjoint
  float* Part = Pg;                         // alias: k_node partials

  k_node_part<<<512, 256, 0, stream>>>(nodef, W_node, Part);
  k_node_sum<<<1024, 256, 0, stream>>>(Part, b_node, hV);
  k_edges<<<16384, 256, 0, stream>>>(coords, mask, W_ee, g_eln, b_eln, Eidx, Eln);
  k_prep<<<8, 256, 0, stream>>>(W_ep, b_ep, WK, bK, WV, bV, WKfold, bK2, WepWV, bV2);
  for (int l = 0; l < 4; l++) {
    k_qproj<<<512, 256, 0, stream>>>(hV, WQ + l * 4096, bQ + l * 64,
                                     WK + l * 8192, WKfold + l * 1024, bK2 + l * 64,
                                     QWn, eqw, qb2);
    k_attn<<<16384, 256, 0, stream>>>(Eln, Eidx, hV, mask, QWn, eqw, qb2, Pg, ats);
    k_upd<<<2048, 256, 0, stream>>>(Pg, ats, WV + l * 8192, WepWV + l * 1024,
                                    bV2 + l * 64, Qb);
    k_resln<<<1024, 256, 0, stream>>>(Qb, WO + l * 4096, bO + l * 64,
                                      g1 + l * 64, b1 + l * 64, hV);
    k_ffn1<<<1024, 256, 0, stream>>>(hV, W1 + l * 16384, bf1 + l * 256, Tb);
    k_ffn2<<<1024, 256, 0, stream>>>(Tb, W2 + l * 16384, bf2 + l * 64,
                                     g2 + l * 64, b2 + l * 64, mask, hV);
  }
  k_out<<<4096, 256, 0, stream>>>(hV, W_out, b_out, (float*)d_out);
}

// Round 14
// 792.641 us; speedup vs baseline: 1.0120x; 1.0011x over previous
//
#include <hip/hip_runtime.h>
#include <hip/hip_fp16.h>

#define L_ 2048
#define NROW 16384
#define FIN 1038

// ---------------- node embedding part: Part[split] = X[:, ks:ke] @ W[ks:ke, :] ----------------
__global__ __launch_bounds__(256) void k_node_part(const float* __restrict__ X,
                                                   const float* __restrict__ W,
                                                   float* __restrict__ Part) {
  const int rb = blockIdx.x >> 2;
  const int split = blockIdx.x & 3;
  const int kStart = split * 260;
  const int kEnd = (split == 3) ? FIN : (kStart + 260);
  const int t = threadIdx.x;
  const int row0 = rb * 128;
  __shared__ float Xs[2][16][132];
  __shared__ float Ws[2][16][64];
  const int ri = t >> 3;
  const int ci = t & 7;
  const int sxr = t >> 2;
  const int sxk = (t & 3) * 4;
  const int swr = t >> 4;
  const int swc = (t & 15) * 4;

  float acc[4][8];
#pragma unroll
  for (int u = 0; u < 4; u++)
#pragma unroll
    for (int v = 0; v < 8; v++) acc[u][v] = 0.f;

  float4 px0, px1, pwv;

#define LOADX(dst, kc, rsub)                                            \
  {                                                                     \
    const int col = (kc) + sxk;                                         \
    const float* xr = &X[(size_t)(row0 + sxr + 64 * (rsub)) * FIN];     \
    float4 v = make_float4(0.f, 0.f, 0.f, 0.f);                         \
    if (col + 4 <= kEnd) v = *(const float4*)&xr[col];                  \
    else {                                                              \
      if (col + 0 < kEnd) v.x = xr[col + 0];                            \
      if (col + 1 < kEnd) v.y = xr[col + 1];                            \
      if (col + 2 < kEnd) v.z = xr[col + 2];                            \
      if (col + 3 < kEnd) v.w = xr[col + 3];                            \
    }                                                                   \
    dst = v;                                                            \
  }
#define LOADW(dst, kc)                                                  \
  {                                                                     \
    const int j = (kc) + swr;                                           \
    dst = (j < kEnd) ? *(const float4*)&W[(size_t)j * 64 + swc]         \
                     : make_float4(0.f, 0.f, 0.f, 0.f);                 \
  }

  LOADX(px0, kStart, 0);
  LOADX(px1, kStart, 1);
  LOADW(pwv, kStart);

  int buf = 0;
  for (int kc = kStart; kc < kEnd; kc += 16) {
    Xs[buf][sxk + 0][sxr] = px0.x;
    Xs[buf][sxk + 1][sxr] = px0.y;
    Xs[buf][sxk + 2][sxr] = px0.z;
    Xs[buf][sxk + 3][sxr] = px0.w;
    Xs[buf][sxk + 0][64 + sxr] = px1.x;
    Xs[buf][sxk + 1][64 + sxr] = px1.y;
    Xs[buf][sxk + 2][64 + sxr] = px1.z;
    Xs[buf][sxk + 3][64 + sxr] = px1.w;
    *(float4*)&Ws[buf][swr][swc] = pwv;
    __syncthreads();
    const int kn = kc + 16;
    if (kn < kEnd) {
      LOADX(px0, kn, 0);
      LOADX(px1, kn, 1);
      LOADW(pwv, kn);
    }
#pragma unroll
    for (int k = 0; k < 16; k++) {
      const float4 xv = *(const float4*)&Xs[buf][k][4 * ri];
      const float4 w0 = *(const float4*)&Ws[buf][k][8 * ci];
      const float4 w1 = *(const float4*)&Ws[buf][k][8 * ci + 4];
      const float xr_[4] = {xv.x, xv.y, xv.z, xv.w};
      const float wc_[8] = {w0.x, w0.y, w0.z, w0.w, w1.x, w1.y, w1.z, w1.w};
#pragma unroll
      for (int u = 0; u < 4; u++)
#pragma unroll
        for (int v = 0; v < 8; v++) acc[u][v] += xr_[u] * wc_[v];
    }
    buf ^= 1;
  }
#undef LOADX
#undef LOADW

  float* P = Part + (size_t)split * (NROW * 64);
#pragma unroll
  for (int u = 0; u < 4; u++) {
    const int row = row0 + 4 * ri + u;
    *(float4*)&P[(size_t)row * 64 + 8 * ci] =
        make_float4(acc[u][0], acc[u][1], acc[u][2], acc[u][3]);
    *(float4*)&P[(size_t)row * 64 + 8 * ci + 4] =
        make_float4(acc[u][4], acc[u][5], acc[u][6], acc[u][7]);
  }
}

// ---------------- hV = sum of 4 partials + bias ----------------
__global__ __launch_bounds__(256) void k_node_sum(const float* __restrict__ Part,
                                                  const float* __restrict__ bias,
                                                  float* __restrict__ out) {
  const int i = (blockIdx.x * 256 + threadIdx.x) * 4;
  const float4 a = *(const float4*)&Part[i];
  const float4 b = *(const float4*)&Part[1048576 + i];
  const float4 c = *(const float4*)&Part[2 * 1048576 + i];
  const float4 d = *(const float4*)&Part[3 * 1048576 + i];
  const float4 bb = *(const float4*)&bias[i & 63];
  float4 o;
  o.x = a.x + b.x + c.x + d.x + bb.x;
  o.y = a.y + b.y + c.y + d.y + bb.y;
  o.z = a.z + b.z + c.z + d.z + bb.z;
  o.w = a.w + b.w + c.w + d.w + bb.w;
  *(float4*)&out[i] = o;
}

// ---------------- edges: distances + histogram-select top-30 + E_ln precompute (R9 proven) ----------------
__global__ __launch_bounds__(256) void k_edges(const float* __restrict__ coords,
                                               const float* __restrict__ mask,
                                               const float* __restrict__ Wee,
                                               const float* __restrict__ geln,
                                               const float* __restrict__ beln,
                                               int* __restrict__ Eidx,
                                               __half* __restrict__ Eln) {
  const int row = blockIdx.x;
  const int b = row >> 11;
  const int t = threadIdx.x;
  const int lane = t & 63, wid = t >> 6;
  __shared__ float sredf[4];
  __shared__ unsigned int hist[2048];
  __shared__ unsigned int wtot[4];
  __shared__ int s_bin, s_need;
  __shared__ int s_lcnt, s_outcnt;
  __shared__ unsigned int s_lkey[64];
  __shared__ int s_lidx[64];
  __shared__ int s_sel[64];
  __shared__ float sD[30];
  __shared__ int sJ[30];
  __shared__ float sWee[16][16];
  __shared__ float sg[16], sb[16];
  __shared__ float sRBF[30][16];

  if (t < 256) sWee[t >> 4][t & 15] = Wee[t];
  if (t < 16) { sg[t] = geln[t]; sb[t] = beln[t]; }
  if (t == 0) { s_lcnt = 0; s_outcnt = 0; }

  const float* cb = coords + (size_t)b * (L_ * 3);
  const int i = row & (L_ - 1);
  const float cix = cb[i * 3 + 0], ciy = cb[i * 3 + 1], ciz = cb[i * 3 + 2];
  const float mi = mask[row];
  const float* mb = mask + (size_t)b * L_;
  float d[8], mj[8];
  float dmax = 0.f;
#pragma unroll
  for (int u = 0; u < 8; u++) {
    int j = t + 256 * u;
    float dx = cix - cb[j * 3 + 0];
    float dy = ciy - cb[j * 3 + 1];
    float dz = ciz - cb[j * 3 + 2];
    float dist = sqrtf(dx * dx + dy * dy + dz * dz + 1e-6f);
    d[u] = dist;
    mj[u] = mb[j];
    dmax = fmaxf(dmax, dist);
  }
#pragma unroll
  for (int off = 32; off; off >>= 1) dmax = fmaxf(dmax, __shfl_xor(dmax, off, 64));
  if (lane == 0) sredf[wid] = dmax;
#pragma unroll
  for (int q = 0; q < 8; q++) hist[t * 8 + q] = 0u;
  __syncthreads();
  dmax = fmaxf(fmaxf(sredf[0], sredf[1]), fmaxf(sredf[2], sredf[3]));
  const float scale = 1024.0f / fmaxf(dmax, 1e-20f);
  float adj[8];
  int bin[8];
#pragma unroll
  for (int u = 0; u < 8; u++) {
    adj[u] = d[u] + (1.f - mi * mj[u]) * dmax;
    int bi = (int)(adj[u] * scale);
    bin[u] = bi < 2047 ? bi : 2047;
    atomicAdd(&hist[bin[u]], 1u);
  }
  __syncthreads();
  unsigned int c[8];
  unsigned int local = 0;
#pragma unroll
  for (int q = 0; q < 8; q++) { c[q] = hist[t * 8 + q]; local += c[q]; }
  unsigned int incl = local;
#pragma unroll
  for (int off = 1; off < 64; off <<= 1) {
    unsigned int v = __shfl_up(incl, off, 64);
    if (lane >= off) incl += v;
  }
  if (lane == 63) wtot[wid] = incl;
  __syncthreads();
  unsigned int excl = incl - local;
  for (int w = 0; w < wid; w++) excl += wtot[w];
  if (excl < 30u && excl + local >= 30u) {
    unsigned int run = excl;
#pragma unroll
    for (int q = 0; q < 8; q++) {
      if (run + c[q] >= 30u) { s_bin = t * 8 + q; s_need = 30 - (int)run; break; }
      run += c[q];
    }
  }
  __syncthreads();
  const int tbin = s_bin;
  int pos[8];
#pragma unroll
  for (int u = 0; u < 8; u++) {
    pos[u] = -1;
    if (bin[u] == tbin) {
      int p = atomicAdd(&s_lcnt, 1);
      if (p < 64) { s_lkey[p] = __float_as_uint(adj[u]); s_lidx[p] = t + 256 * u; pos[u] = p; }
    }
  }
  __syncthreads();
  {
    int n = s_lcnt < 64 ? s_lcnt : 64;
    if (t < n) {
      unsigned int k0 = s_lkey[t];
      int j0 = s_lidx[t];
      int r = 0;
      for (int m = 0; m < n; m++) {
        unsigned int km = s_lkey[m];
        r += (km < k0) || (km == k0 && s_lidx[m] < j0);
      }
      s_sel[t] = (r < s_need) ? 1 : 0;
    }
  }
  __syncthreads();
#pragma unroll
  for (int u = 0; u < 8; u++) {
    bool sel = (bin[u] < tbin) || (pos[u] >= 0 && s_sel[pos[u]]);
    if (sel) {
      int o = atomicAdd(&s_outcnt, 1);
      if (o < 30) { sJ[o] = t + 256 * u; sD[o] = adj[u]; }
    }
  }
  __syncthreads();
  if (t < 30) Eidx[(size_t)row * 30 + t] = sJ[t];
  for (int o = t; o < 480; o += 256) {
    int k = o >> 4, s = o & 15;
    float mu = 2.0f + (4.0f / 3.0f) * (float)s;
    float z = (sD[k] - mu) * 0.8f;
    sRBF[k][s] = __expf(-z * z);
  }
  __syncthreads();
  if (t < 240) {
    int k = t >> 3, p = t & 7;
    int c0 = p * 2, c1 = c0 + 1;
    float e0 = 0.f, e1 = 0.f;
#pragma unroll
    for (int s = 0; s < 16; s++) {
      float r = sRBF[k][s];
      e0 += r * sWee[s][c0];
      e1 += r * sWee[s][c1];
    }
    float s1 = e0 + e1, s2 = e0 * e0 + e1 * e1;
#pragma unroll
    for (int m = 1; m < 8; m <<= 1) {
      s1 += __shfl_xor(s1, m, 64);
      s2 += __shfl_xor(s2, m, 64);
    }
    float mean = s1 * (1.f / 16.f);
    float var = s2 * (1.f / 16.f) - mean * mean;
    float inv = rsqrtf(var + 1e-5f);
    Eln[(size_t)row * 480 + k * 16 + c0] = __float2half((e0 - mean) * inv * sg[c0] + sb[c0]);
    Eln[(size_t)row * 480 + k * 16 + c1] = __float2half((e1 - mean) * inv * sg[c1] + sb[c1]);
  }
}

// ---------------- per-layer weight folding ----------------
__global__ __launch_bounds__(256) void k_prep(const float* __restrict__ Wep,
                                              const float* __restrict__ bep,
                                              const float* __restrict__ WK,
                                              const float* __restrict__ bK,
                                              const float* __restrict__ WV,
                                              const float* __restrict__ bV,
                                              float* __restrict__ WKfold,
                                              float* __restrict__ bK2,
                                              float* __restrict__ WepWV,
                                              float* __restrict__ bV2) {
  const int l = blockIdx.x >> 1, isV = blockIdx.x & 1;
  const float* W = (isV ? WV : WK) + (size_t)l * 8192;
  const float* bsrc = (isV ? bV : bK) + l * 64;
  float* fold = (isV ? WepWV : WKfold) + l * 1024;
  float* b2 = (isV ? bV2 : bK2) + l * 64;
  __shared__ float sW[64][64];
  __shared__ float sWep[16][64];
  const int t = threadIdx.x;
  for (int q = 0; q < 16; q++) { int i = t + 256 * q; sW[i >> 6][i & 63] = W[i]; }
  for (int q = 0; q < 4; q++)  { int i = t + 256 * q; sWep[i >> 6][i & 63] = Wep[i]; }
  __syncthreads();
  const int c = t & 63, rg = t >> 6;
  for (int r = rg; r < 16; r += 4) {
    float a = 0.f;
    for (int s = 0; s < 64; s++) a += sWep[r][s] * sW[s][c];
    fold[r * 64 + c] = a;
  }
  if (t < 64) {
    float a = bsrc[t];
    for (int s = 0; s < 64; s++) a += bep[s] * sW[s][t];
    b2[t] = a;
  }
}

// ---------------- k_qproj: fused Q=hV@WQ+bQ (LDS) -> QWn/eqw/qb2; 512 blocks x 32 rows ----------------
__global__ __launch_bounds__(256) void k_qproj(const float* __restrict__ hV,
                                               const float* __restrict__ WQ,
                                               const float* __restrict__ bQ,
                                               const float* __restrict__ WK,
                                               const float* __restrict__ WKfold,
                                               const float* __restrict__ bK2,
                                               float* __restrict__ QWn,
                                               float* __restrict__ eqw,
                                               float* __restrict__ qb2) {
  __shared__ float sX[32 * 68];
  __shared__ float sW[64 * 64];
  __shared__ float sb[64];
  const int t = threadIdx.x;
  const int row0 = blockIdx.x * 32;
  const int c = t & 63, rg = t >> 6;
  const int h = t >> 6, s2 = t & 63;
  const float4 wk0 = *(const float4*)&WK[(size_t)(64 + s2) * 64 + h * 16 + 0];
  const float4 wk1 = *(const float4*)&WK[(size_t)(64 + s2) * 64 + h * 16 + 4];
  const float4 wk2 = *(const float4*)&WK[(size_t)(64 + s2) * 64 + h * 16 + 8];
  const float4 wk3 = *(const float4*)&WK[(size_t)(64 + s2) * 64 + h * 16 + 12];
  const int rb4 = (t >> 4) & 3, tt = t & 15;
  const float4 wf0 = *(const float4*)&WKfold[tt * 64 + h * 16 + 0];
  const float4 wf1 = *(const float4*)&WKfold[tt * 64 + h * 16 + 4];
  const float4 wf2 = *(const float4*)&WKfold[tt * 64 + h * 16 + 8];
  const float4 wf3 = *(const float4*)&WKfold[tt * 64 + h * 16 + 12];
#pragma unroll
  for (int q = 0; q < 8; q++) {
    int i = t + 256 * q;
    sX[(i >> 6) * 68 + (i & 63)] = hV[(size_t)(row0 + (i >> 6)) * 64 + (i & 63)];
  }
#pragma unroll
  for (int q = 0; q < 16; q++) {
    int i = t + 256 * q;
    sW[i] = WQ[i];
  }
  if (t < 64) sb[t] = bK2[t];
  __syncthreads();
  float acc[8];
#pragma unroll
  for (int u = 0; u < 8; u++) acc[u] = 0.f;
#pragma unroll
  for (int s0 = 0; s0 < 64; s0 += 4) {
    float w0 = sW[s0 * 64 + c], w1 = sW[(s0 + 1) * 64 + c];
    float w2 = sW[(s0 + 2) * 64 + c], w3 = sW[(s0 + 3) * 64 + c];
#pragma unroll
    for (int u = 0; u < 8; u++) {
      const float4 a = *(const float4*)&sX[(rg + 4 * u) * 68 + s0];
      acc[u] += a.x * w0 + a.y * w1 + a.z * w2 + a.w * w3;
    }
  }
  __syncthreads();
  const float bb = bQ[c];
  float* sQ = sW;
#pragma unroll
  for (int u = 0; u < 8; u++) sQ[(rg + 4 * u) * 68 + c] = acc[u] + bb;
  __syncthreads();
  for (int r = 0; r < 32; r++) {
    const float4 q0 = *(const float4*)&sQ[r * 68 + h * 16 + 0];
    const float4 q1 = *(const float4*)&sQ[r * 68 + h * 16 + 4];
    const float4 q2 = *(const float4*)&sQ[r * 68 + h * 16 + 8];
    const float4 q3 = *(const float4*)&sQ[r * 68 + h * 16 + 12];
    float a = q0.x * wk0.x + q0.y * wk0.y + q0.z * wk0.z + q0.w * wk0.w
            + q1.x * wk1.x + q1.y * wk1.y + q1.z * wk1.z + q1.w * wk1.w
            + q2.x * wk2.x + q2.y * wk2.y + q2.z * wk2.z + q2.w * wk2.w
            + q3.x * wk3.x + q3.y * wk3.y + q3.z * wk3.z + q3.w * wk3.w;
    QWn[(size_t)(row0 + r) * 256 + h * 64 + s2] = a;
  }
  for (int rr = 0; rr < 8; rr++) {
    const int r = rr * 4 + rb4;
    const float4 q0 = *(const float4*)&sQ[r * 68 + h * 16 + 0];
    const float4 q1 = *(const float4*)&sQ[r * 68 + h * 16 + 4];
    const float4 q2 = *(const float4*)&sQ[r * 68 + h * 16 + 8];
    const float4 q3 = *(const float4*)&sQ[r * 68 + h * 16 + 12];
    float a = q0.x * wf0.x + q0.y * wf0.y + q0.z * wf0.z + q0.w * wf0.w
            + q1.x * wf1.x + q1.y * wf1.y + q1.z * wf1.z + q1.w * wf1.w
            + q2.x * wf2.x + q2.y * wf2.y + q2.z * wf2.z + q2.w * wf2.w
            + q3.x * wf3.x + q3.y * wf3.y + q3.z * wf3.z + q3.w * wf3.w;
    eqw[(size_t)(row0 + r) * 64 + h * 16 + tt] = a;
  }
  if (t < 128) {
    const int r = t >> 2, h2 = t & 3;
    float a = 0.f;
#pragma unroll
    for (int d = 0; d < 16; d++) a += sQ[r * 68 + h2 * 16 + d] * sb[h2 * 16 + d];
    qb2[(size_t)(row0 + r) * 4 + h2] = a;
  }
}

// ---------------- k_attn v4: float2 LDS (strides 66/18), split-k P-phase ----------------
__global__ __launch_bounds__(256) void k_attn(
    const __half* __restrict__ Eln, const int* __restrict__ Eidx,
    const float* __restrict__ hV, const float* __restrict__ mask,
    const float* __restrict__ QWn, const float* __restrict__ eqw,
    const float* __restrict__ qb2,
    float* __restrict__ Pg, float* __restrict__ attsum) {
  const int row = blockIdx.x;
  const int b = row >> 11;
  const int t = threadIdx.x;
  const int lane = t & 63, wid = t >> 6;
  __shared__ float sHV[30 * 66];  // stride 66: even (b64-aligned), 2-way bank aliasing = free
  __shared__ float sE[30 * 18];   // stride 18: even, 2-way aliasing
  __shared__ float sQn[256];
  __shared__ float swq[64];
  __shared__ float sqb2[4];
  __shared__ float smk[32];
  __shared__ float satt4[32 * 4];
  __shared__ float sPc[4][4][64];
  __shared__ float sEc[4][4][16];

  sQn[t] = QWn[(size_t)row * 256 + t];
  if (t < 64) swq[t] = eqw[(size_t)row * 64 + t];
  if (t < 4) sqb2[t] = qb2[(size_t)row * 4 + t];
  if (t < 30) smk[t] = mask[(b << 11) + Eidx[(size_t)row * 30 + t]] * mask[row];
  if (t < 240) {
    const __half2 h2v = *(const __half2*)&Eln[(size_t)row * 480 + 2 * t];
    const float2 f2 = __half22float2(h2v);
    const int k = (2 * t) >> 4, c = (2 * t) & 15;
    *(float2*)&sE[k * 18 + c] = f2;
  }
#pragma unroll
  for (int q = 0; q < 4; q++) {
    int o = t + 256 * q;
    if (o < 960) {
      const int k = o >> 5, c2 = (o & 31) * 2;
      const int j = Eidx[(size_t)row * 30 + k];
      const float2 v = *(const float2*)&hV[((size_t)(b << 11) + j) * 64 + c2];
      *(float2*)&sHV[k * 66 + c2] = v;
    }
  }
  __syncthreads();

  // ---- logits: wave = head; float2 LDS reads (half the DS instructions) ----
  const int kk = (lane < 30) ? lane : (lane - 30);
  const int sbase = (lane < 30) ? 0 : 32;
  const int tbase = (lane < 30) ? 0 : 8;
  float lg = 0.f;
  if (lane < 60) {
#pragma unroll
    for (int s = 0; s < 32; s += 2) {
      const float2 hv2 = *(const float2*)&sHV[kk * 66 + sbase + s];
      const float2 qn2 = *(const float2*)&sQn[wid * 64 + sbase + s];
      lg += hv2.x * qn2.x + hv2.y * qn2.y;
    }
#pragma unroll
    for (int tt = 0; tt < 8; tt += 2) {
      const float2 e2 = *(const float2*)&sE[kk * 18 + tbase + tt];
      const float2 w2 = *(const float2*)&swq[wid * 16 + tbase + tt];
      lg += e2.x * w2.x + e2.y * w2.y;
    }
  }
  float oth = __shfl(lg, lane + 30, 64);
  float mk = (lane < 30) ? smk[lane] : 0.f;
  float lgv = (lane < 30 && mk > 0.f) ? (lg + oth + sqb2[wid]) * 0.25f
                                      : -3.402823466e38f;
  float mx = lgv;
#pragma unroll
  for (int off = 16; off; off >>= 1) mx = fmaxf(mx, __shfl_xor(mx, off, 64));
  float e = (lane < 30) ? __expf(lgv - mx) : 0.f;
  float den = e;
#pragma unroll
  for (int off = 16; off; off >>= 1) den += __shfl_xor(den, off, 64);
  float att = e * (1.f / den) * mk;
  float ss = att;
#pragma unroll
  for (int off = 16; off; off >>= 1) ss += __shfl_xor(ss, off, 64);
  if (lane == 0) attsum[(size_t)row * 4 + wid] = ss;
  if (lane < 30) satt4[lane * 4 + wid] = att;
  __syncthreads();

  // ---- P-phase: wave w covers k-range, accumulating ALL 4 heads ----
  const int k0 = wid * 8;
  const int knum = (wid == 3) ? 6 : 8;
  float pn0 = 0.f, pn1 = 0.f, pn2 = 0.f, pn3 = 0.f;
  float ea0 = 0.f, ea1 = 0.f, ea2 = 0.f, ea3 = 0.f;
  for (int u = 0; u < knum; u++) {
    const int k2 = k0 + u;
    const float4 a4 = *(const float4*)&satt4[k2 * 4];
    const float hvv = sHV[k2 * 66 + lane];
    pn0 += a4.x * hvv; pn1 += a4.y * hvv; pn2 += a4.z * hvv; pn3 += a4.w * hvv;
    const float ev = (lane < 16) ? sE[k2 * 18 + lane] : 0.f;
    ea0 += a4.x * ev; ea1 += a4.y * ev; ea2 += a4.z * ev; ea3 += a4.w * ev;
  }
  sPc[wid][0][lane] = pn0;
  sPc[wid][1][lane] = pn1;
  sPc[wid][2][lane] = pn2;
  sPc[wid][3][lane] = pn3;
  if (lane < 16) {
    sEc[wid][0][lane] = ea0;
    sEc[wid][1][lane] = ea1;
    sEc[wid][2][lane] = ea2;
    sEc[wid][3][lane] = ea3;
  }
  __syncthreads();
  float pv = sPc[0][wid][lane] + sPc[1][wid][lane] + sPc[2][wid][lane] + sPc[3][wid][lane];
  float* pr = Pg + (size_t)row * 320 + wid * 80;
  pr[lane] = pv;
  if (lane < 16) {
    float ev2 = sEc[0][wid][lane] + sEc[1][wid][lane] + sEc[2][wid][lane] + sEc[3][wid][lane];
    pr[64 + lane] = ev2;
  }
}

// ---------------- upd = Pnode @ WV_bot + eatt @ WepWV + ats*bV2 ----------------
__global__ __launch_bounds__(256) void k_upd(const float* __restrict__ Pg,
                                             const float* __restrict__ ats,
                                             const float* __restrict__ WV,
                                             const float* __restrict__ WepWV,
                                             const float* __restrict__ bV2,
                                             float* __restrict__ U) {
  __shared__ float sWVb[64 * 64];
  __shared__ float sWf[16 * 64];
  __shared__ float sb[64];
  __shared__ float sP[8 * 320];
  const int t = threadIdx.x;
  const int row0 = blockIdx.x * 8;
  for (int q = 0; q < 16; q++) {
    int i = t + 256 * q;
    sWVb[i] = WV[4096 + i];
  }
  for (int q = 0; q < 4; q++) {
    int i = t + 256 * q;
    sWf[i] = WepWV[i];
  }
  if (t < 64) sb[t] = bV2[t];
  for (int q = 0; q < 10; q++) {
    int i = t + 256 * q;
    sP[i] = Pg[(size_t)row0 * 320 + i];
  }
  __syncthreads();
  const int c = t & 63, rg = t >> 6;
  const int h = c >> 4;
  const int r0 = rg * 2;
  float a0 = 0.f, a1 = 0.f;
#pragma unroll 8
  for (int s = 0; s < 64; s++) {
    float w = sWVb[s * 64 + c];
    a0 += sP[r0 * 320 + h * 80 + s] * w;
    a1 += sP[(r0 + 1) * 320 + h * 80 + s] * w;
  }
#pragma unroll
  for (int tt = 0; tt < 16; tt++) {
    float w = sWf[tt * 64 + c];
    a0 += sP[r0 * 320 + h * 80 + 64 + tt] * w;
    a1 += sP[(r0 + 1) * 320 + h * 80 + 64 + tt] * w;
  }
  const float bv = sb[c];
  const int grow = row0 + r0;
  U[(size_t)grow * 64 + c] = a0 + ats[(size_t)grow * 4 + h] * bv;
  U[(size_t)(grow + 1) * 64 + c] = a1 + ats[(size_t)(grow + 1) * 4 + h] * bv;
}

// ---------------- hV = LN(hV + U @ WO + bO) ----------------
__global__ __launch_bounds__(256) void k_resln(const float* __restrict__ U,
                                               const float* __restrict__ WO,
                                               const float* __restrict__ bO,
                                               const float* __restrict__ g,
                                               const float* __restrict__ bb,
                                               float* __restrict__ hV) {
  __shared__ float sUt[64][16];
  __shared__ float sW[64][64];
  __shared__ float sO[16][64];
  const int t = threadIdx.x;
  const int row0 = blockIdx.x * 16;
#pragma unroll
  for (int q = 0; q < 4; q++) {
    int i = t + 256 * q;
    int r = i >> 6, cc = i & 63;
    sUt[cc][r] = U[(size_t)(row0 + r) * 64 + cc];
  }
#pragma unroll
  for (int q = 0; q < 16; q++) {
    int i = t + 256 * q;
    sW[i >> 6][i & 63] = WO[i];
  }
  __syncthreads();
  const int c = t & 63, rg = t >> 6;
  float acc[4] = {0.f, 0.f, 0.f, 0.f};
#pragma unroll
  for (int s = 0; s < 64; s++) {
    float w = sW[s][c];
    const float4 x = *(const float4*)&sUt[s][rg * 4];
    acc[0] += x.x * w; acc[1] += x.y * w; acc[2] += x.z * w; acc[3] += x.w * w;
  }
  const float bv = bO[c];
#pragma unroll
  for (int u = 0; u < 4; u++) sO[rg * 4 + u][c] = acc[u] + bv;
  __syncthreads();
  const int lane = t & 63, wv = t >> 6;
  const float gv = g[lane], bbv = bb[lane];
  for (int r = wv; r < 16; r += 4) {
    const int row = row0 + r;
    float x = hV[(size_t)row * 64 + lane] + sO[r][lane];
    float s1 = x, s2 = x * x;
#pragma unroll
    for (int off = 32; off; off >>= 1) {
      s1 += __shfl_xor(s1, off, 64);
      s2 += __shfl_xor(s2, off, 64);
    }
    float m = s1 * (1.f / 64.f);
    float var = s2 * (1.f / 64.f) - m * m;
    float inv = rsqrtf(var + 1e-5f);
    hV[(size_t)row * 64 + lane] = (x - m) * inv * gv + bbv;
  }
}

// ---------------- T = relu(hV @ W1 + bf1) ----------------
__global__ __launch_bounds__(256) void k_ffn1(const float* __restrict__ X,
                                              const float* __restrict__ W1,
                                              const float* __restrict__ bf1,
                                              float* __restrict__ T) {
  __shared__ float sXt[64][16];
  __shared__ float sW[32][256];
  const int t = threadIdx.x;
  const int row0 = blockIdx.x * 16;
#pragma unroll
  for (int q = 0; q < 4; q++) {
    int i = t + 256 * q;
    int r = i >> 6, cc = i & 63;
    sXt[cc][r] = X[(size_t)(row0 + r) * 64 + cc];
  }
  float acc[16];
#pragma unroll
  for (int u = 0; u < 16; u++) acc[u] = 0.f;
  for (int kc = 0; kc < 64; kc += 32) {
    __syncthreads();
#pragma unroll
    for (int q = 0; q < 32; q++) {
      int i = t + 256 * q;
      sW[i >> 8][i & 255] = W1[(size_t)(kc + (i >> 8)) * 256 + (i & 255)];
    }
    __syncthreads();
#pragma unroll
    for (int s = 0; s < 32; s++) {
      float w = sW[s][t];
      const float4 x0 = *(const float4*)&sXt[kc + s][0];
      const float4 x1 = *(const float4*)&sXt[kc + s][4];
      const float4 x2 = *(const float4*)&sXt[kc + s][8];
      const float4 x3 = *(const float4*)&sXt[kc + s][12];
      acc[0] += x0.x * w; acc[1] += x0.y * w; acc[2] += x0.z * w; acc[3] += x0.w * w;
      acc[4] += x1.x * w; acc[5] += x1.y * w; acc[6] += x1.z * w; acc[7] += x1.w * w;
      acc[8] += x2.x * w; acc[9] += x2.y * w; acc[10] += x2.z * w; acc[11] += x2.w * w;
      acc[12] += x3.x * w; acc[13] += x3.y * w; acc[14] += x3.z * w; acc[15] += x3.w * w;
    }
  }
  const float bv = bf1[t];
#pragma unroll
  for (int r = 0; r < 16; r++)
    T[(size_t)(row0 + r) * 256 + t] = fmaxf(acc[r] + bv, 0.f);
}

// ---------------- hV = LN(hV + T @ W2 + bf2) * mask ----------------
__global__ __launch_bounds__(256) void k_ffn2(const float* __restrict__ T,
                                              const float* __restrict__ W2,
                                              const float* __restrict__ bf2,
                                              const float* __restrict__ g,
                                              const float* __restrict__ bb,
                                              const float* __restrict__ mask,
                                              float* __restrict__ hV) {
  __shared__ float sTt[64][16];
  __shared__ float sW[64][64];
  __shared__ float sO[16][64];
  const int t = threadIdx.x;
  const int row0 = blockIdx.x * 16;
  const int c = t & 63, rg = t >> 6;
  float acc[4] = {0.f, 0.f, 0.f, 0.f};
  for (int kc = 0; kc < 256; kc += 64) {
    __syncthreads();
#pragma unroll
    for (int q = 0; q < 4; q++) {
      int i = t + 256 * q;
      int r = i >> 6, cc = i & 63;
      sTt[cc][r] = T[(size_t)(row0 + r) * 256 + kc + cc];
    }
#pragma unroll
    for (int q = 0; q < 16; q++) {
      int i = t + 256 * q;
      sW[i >> 6][i & 63] = W2[(size_t)(kc + (i >> 6)) * 64 + (i & 63)];
    }
    __syncthreads();
#pragma unroll
    for (int s = 0; s < 64; s++) {
      float w = sW[s][c];
      const float4 x = *(const float4*)&sTt[s][rg * 4];
      acc[0] += x.x * w; acc[1] += x.y * w; acc[2] += x.z * w; acc[3] += x.w * w;
    }
  }
  const float bv = bf2[c];
#pragma unroll
  for (int u = 0; u < 4; u++) sO[rg * 4 + u][c] = acc[u] + bv;
  __syncthreads();
  const int lane = t & 63, wv = t >> 6;
  const float gv = g[lane], bbv = bb[lane];
  for (int r = wv; r < 16; r += 4) {
    const int row = row0 + r;
    float x = hV[(size_t)row * 64 + lane] + sO[r][lane];
    float s1 = x, s2 = x * x;
#pragma unroll
    for (int off = 32; off; off >>= 1) {
      s1 += __shfl_xor(s1, off, 64);
      s2 += __shfl_xor(s2, off, 64);
    }
    float m = s1 * (1.f / 64.f);
    float var = s2 * (1.f / 64.f) - m * m;
    float inv = rsqrtf(var + 1e-5f);
    float y = (x - m) * inv * gv + bbv;
    hV[(size_t)row * 64 + lane] = y * mask[row];
  }
}

// ---------------- out = hV @ W_out + b_out ----------------
__global__ __launch_bounds__(256) void k_out(const float* __restrict__ hV,
                                             const float* __restrict__ Wo,
                                             const float* __restrict__ bo,
                                             float* __restrict__ out) {
  const int t = threadIdx.x;
  const int lane = t & 63, wv = t >> 6;
  const int row = blockIdx.x * 4 + wv;
  float v = hV[(size_t)row * 64 + lane] * Wo[lane];
#pragma unroll
  for (int off = 32; off; off >>= 1) v += __shfl_xor(v, off, 64);
  if (lane == 0) out[row] = v + bo[0];
}

extern "C" void kernel_launch(void* const* d_in, const int* in_sizes, int n_in,
                              void* d_out, int out_size, void* d_ws, size_t ws_size,
                              hipStream_t stream) {
  const float* coords = (const float*)d_in[0];
  const float* nodef = (const float*)d_in[1];
  const float* mask = (const float*)d_in[2];
  const float* W_node = (const float*)d_in[3];
  const float* b_node = (const float*)d_in[4];
  const float* W_ee = (const float*)d_in[5];
  const float* g_eln = (const float*)d_in[6];
  const float* b_eln = (const float*)d_in[7];
  const float* W_ep = (const float*)d_in[8];
  const float* b_ep = (const float*)d_in[9];
  const float* WQ = (const float*)d_in[10];
  const float* bQ = (const float*)d_in[11];
  const float* WK = (const float*)d_in[12];
  const float* bK = (const float*)d_in[13];
  const float* WV = (const float*)d_in[14];
  const float* bV = (const float*)d_in[15];
  const float* WO = (const float*)d_in[16];
  const float* bO = (const float*)d_in[17];
  const float* g1 = (const float*)d_in[18];
  const float* b1 = (const float*)d_in[19];
  const float* W1 = (const float*)d_in[20];
  const float* bf1 = (const float*)d_in[21];
  const float* W2 = (const float*)d_in[22];
  const float* bf2 = (const float*)d_in[23];
  const float* g2 = (const float*)d_in[24];
  const float* b2 = (const float*)d_in[25];
  const float* W_out = (const float*)d_in[26];
  const float* b_out = (const float*)d_in[27];

  float* ws = (float*)d_ws;
  float* hV = ws;                           // 1,048,576 f
  float* Qb = hV + 1048576;                 // 1,048,576 f  (U)
  float* QWn = Qb + 1048576;                // 4,194,304 f  (alias Tb)
  float* eqw = QWn + 4194304;               // 1,048,576 f
  float* Pg = eqw + 1048576;                // 5,242,880 f  (alias Part)
  float* qb2 = Pg + 5242880;                // 65,536 f
  float* ats = qb2 + 65536;                 // 65,536 f
  int* Eidx = (int*)(ats + 65536);          // 491,520 i
  __half* Eln = (__half*)(Eidx + 491520);   // 7,864,320 h
  float* WKfold = (float*)(Eln + 7864320);  // 4,096 f
  float* bK2 = WKfold + 4096;               // 256 f
  float* WepWV = bK2 + 256;                 // 4,096 f
  float* bV2 = WepWV + 4096;                // 256 f
  float* Tb = QWn;                          // alias: lifetime disjoint
  float* Part = Pg;                         // alias: k_node partials

  k_node_part<<<512, 256, 0, stream>>>(nodef, W_node, Part);
  k_node_sum<<<1024, 256, 0, stream>>>(Part, b_node, hV);
  k_edges<<<16384, 256, 0, stream>>>(coords, mask, W_ee, g_eln, b_eln, Eidx, Eln);
  k_prep<<<8, 256, 0, stream>>>(W_ep, b_ep, WK, bK, WV, bV, WKfold, bK2, WepWV, bV2);
  for (int l = 0; l < 4; l++) {
    k_qproj<<<512, 256, 0, stream>>>(hV, WQ + l * 4096, bQ + l * 64,
                                     WK + l * 8192, WKfold + l * 1024, bK2 + l * 64,
                                     QWn, eqw, qb2);
    k_attn<<<16384, 256, 0, stream>>>(Eln, Eidx, hV, mask, QWn, eqw, qb2, Pg, ats);
    k_upd<<<2048, 256, 0, stream>>>(Pg, ats, WV + l * 8192, WepWV + l * 1024,
                                    bV2 + l * 64, Qb);
    k_resln<<<1024, 256, 0, stream>>>(Qb, WO + l * 4096, bO + l * 64,
                                      g1 + l * 64, b1 + l * 64, hV);
    k_ffn1<<<1024, 256, 0, stream>>>(hV, W1 + l * 16384, bf1 + l * 256, Tb);
    k_ffn2<<<1024, 256, 0, stream>>>(Tb, W2 + l * 16384, bf2 + l * 64,
                                     g2 + l * 64, b2 + l * 64, mask, hV);
  }
  k_out<<<4096, 256, 0, stream>>>(hV, W_out, b_out, (float*)d_out);
}

// Round 15
// 790.143 us; speedup vs baseline: 1.0152x; 1.0032x over previous
//
#include <hip/hip_runtime.h>
#include <hip/hip_fp16.h>

#define L_ 2048
#define NROW 16384
#define FIN 1038

// ---------------- node embedding part: Part[split] = X[:, ks:ke] @ W[ks:ke, :] ----------------
__global__ __launch_bounds__(256) void k_node_part(const float* __restrict__ X,
                                                   const float* __restrict__ W,
                                                   float* __restrict__ Part) {
  const int rb = blockIdx.x >> 2;
  const int split = blockIdx.x & 3;
  const int kStart = split * 260;
  const int kEnd = (split == 3) ? FIN : (kStart + 260);
  const int t = threadIdx.x;
  const int row0 = rb * 128;
  __shared__ float Xs[2][16][132];
  __shared__ float Ws[2][16][64];
  const int ri = t >> 3;
  const int ci = t & 7;
  const int sxr = t >> 2;
  const int sxk = (t & 3) * 4;
  const int swr = t >> 4;
  const int swc = (t & 15) * 4;

  float acc[4][8];
#pragma unroll
  for (int u = 0; u < 4; u++)
#pragma unroll
    for (int v = 0; v < 8; v++) acc[u][v] = 0.f;

  float4 px0, px1, pwv;

#define LOADX(dst, kc, rsub)                                            \
  {                                                                     \
    const int col = (kc) + sxk;                                         \
    const float* xr = &X[(size_t)(row0 + sxr + 64 * (rsub)) * FIN];     \
    float4 v = make_float4(0.f, 0.f, 0.f, 0.f);                         \
    if (col + 4 <= kEnd) v = *(const float4*)&xr[col];                  \
    else {                                                              \
      if (col + 0 < kEnd) v.x = xr[col + 0];                            \
      if (col + 1 < kEnd) v.y = xr[col + 1];                            \
      if (col + 2 < kEnd) v.z = xr[col + 2];                            \
      if (col + 3 < kEnd) v.w = xr[col + 3];                            \
    }                                                                   \
    dst = v;                                                            \
  }
#define LOADW(dst, kc)                                                  \
  {                                                                     \
    const int j = (kc) + swr;                                           \
    dst = (j < kEnd) ? *(const float4*)&W[(size_t)j * 64 + swc]         \
                     : make_float4(0.f, 0.f, 0.f, 0.f);                 \
  }

  LOADX(px0, kStart, 0);
  LOADX(px1, kStart, 1);
  LOADW(pwv, kStart);

  int buf = 0;
  for (int kc = kStart; kc < kEnd; kc += 16) {
    Xs[buf][sxk + 0][sxr] = px0.x;
    Xs[buf][sxk + 1][sxr] = px0.y;
    Xs[buf][sxk + 2][sxr] = px0.z;
    Xs[buf][sxk + 3][sxr] = px0.w;
    Xs[buf][sxk + 0][64 + sxr] = px1.x;
    Xs[buf][sxk + 1][64 + sxr] = px1.y;
    Xs[buf][sxk + 2][64 + sxr] = px1.z;
    Xs[buf][sxk + 3][64 + sxr] = px1.w;
    *(float4*)&Ws[buf][swr][swc] = pwv;
    __syncthreads();
    const int kn = kc + 16;
    if (kn < kEnd) {
      LOADX(px0, kn, 0);
      LOADX(px1, kn, 1);
      LOADW(pwv, kn);
    }
#pragma unroll
    for (int k = 0; k < 16; k++) {
      const float4 xv = *(const float4*)&Xs[buf][k][4 * ri];
      const float4 w0 = *(const float4*)&Ws[buf][k][8 * ci];
      const float4 w1 = *(const float4*)&Ws[buf][k][8 * ci + 4];
      const float xr_[4] = {xv.x, xv.y, xv.z, xv.w};
      const float wc_[8] = {w0.x, w0.y, w0.z, w0.w, w1.x, w1.y, w1.z, w1.w};
#pragma unroll
      for (int u = 0; u < 4; u++)
#pragma unroll
        for (int v = 0; v < 8; v++) acc[u][v] += xr_[u] * wc_[v];
    }
    buf ^= 1;
  }
#undef LOADX
#undef LOADW

  float* P = Part + (size_t)split * (NROW * 64);
#pragma unroll
  for (int u = 0; u < 4; u++) {
    const int row = row0 + 4 * ri + u;
    *(float4*)&P[(size_t)row * 64 + 8 * ci] =
        make_float4(acc[u][0], acc[u][1], acc[u][2], acc[u][3]);
    *(float4*)&P[(size_t)row * 64 + 8 * ci + 4] =
        make_float4(acc[u][4], acc[u][5], acc[u][6], acc[u][7]);
  }
}

// ---------------- hV = sum of 4 partials + bias ----------------
__global__ __launch_bounds__(256) void k_node_sum(const float* __restrict__ Part,
                                                  const float* __restrict__ bias,
                                                  float* __restrict__ out) {
  const int i = (blockIdx.x * 256 + threadIdx.x) * 4;
  const float4 a = *(const float4*)&Part[i];
  const float4 b = *(const float4*)&Part[1048576 + i];
  const float4 c = *(const float4*)&Part[2 * 1048576 + i];
  const float4 d = *(const float4*)&Part[3 * 1048576 + i];
  const float4 bb = *(const float4*)&bias[i & 63];
  float4 o;
  o.x = a.x + b.x + c.x + d.x + bb.x;
  o.y = a.y + b.y + c.y + d.y + bb.y;
  o.z = a.z + b.z + c.z + d.z + bb.z;
  o.w = a.w + b.w + c.w + d.w + bb.w;
  *(float4*)&out[i] = o;
}

// ---------------- edges: distances + histogram-select top-30 + E_ln precompute (R9 proven) ----------------
__global__ __launch_bounds__(256) void k_edges(const float* __restrict__ coords,
                                               const float* __restrict__ mask,
                                               const float* __restrict__ Wee,
                                               const float* __restrict__ geln,
                                               const float* __restrict__ beln,
                                               int* __restrict__ Eidx,
                                               __half* __restrict__ Eln) {
  const int row = blockIdx.x;
  const int b = row >> 11;
  const int t = threadIdx.x;
  const int lane = t & 63, wid = t >> 6;
  __shared__ float sredf[4];
  __shared__ unsigned int hist[2048];
  __shared__ unsigned int wtot[4];
  __shared__ int s_bin, s_need;
  __shared__ int s_lcnt, s_outcnt;
  __shared__ unsigned int s_lkey[64];
  __shared__ int s_lidx[64];
  __shared__ int s_sel[64];
  __shared__ float sD[30];
  __shared__ int sJ[30];
  __shared__ float sWee[16][16];
  __shared__ float sg[16], sb[16];
  __shared__ float sRBF[30][16];

  if (t < 256) sWee[t >> 4][t & 15] = Wee[t];
  if (t < 16) { sg[t] = geln[t]; sb[t] = beln[t]; }
  if (t == 0) { s_lcnt = 0; s_outcnt = 0; }

  const float* cb = coords + (size_t)b * (L_ * 3);
  const int i = row & (L_ - 1);
  const float cix = cb[i * 3 + 0], ciy = cb[i * 3 + 1], ciz = cb[i * 3 + 2];
  const float mi = mask[row];
  const float* mb = mask + (size_t)b * L_;
  float d[8], mj[8];
  float dmax = 0.f;
#pragma unroll
  for (int u = 0; u < 8; u++) {
    int j = t + 256 * u;
    float dx = cix - cb[j * 3 + 0];
    float dy = ciy - cb[j * 3 + 1];
    float dz = ciz - cb[j * 3 + 2];
    float dist = sqrtf(dx * dx + dy * dy + dz * dz + 1e-6f);
    d[u] = dist;
    mj[u] = mb[j];
    dmax = fmaxf(dmax, dist);
  }
#pragma unroll
  for (int off = 32; off; off >>= 1) dmax = fmaxf(dmax, __shfl_xor(dmax, off, 64));
  if (lane == 0) sredf[wid] = dmax;
#pragma unroll
  for (int q = 0; q < 8; q++) hist[t * 8 + q] = 0u;
  __syncthreads();
  dmax = fmaxf(fmaxf(sredf[0], sredf[1]), fmaxf(sredf[2], sredf[3]));
  const float scale = 1024.0f / fmaxf(dmax, 1e-20f);
  float adj[8];
  int bin[8];
#pragma unroll
  for (int u = 0; u < 8; u++) {
    adj[u] = d[u] + (1.f - mi * mj[u]) * dmax;
    int bi = (int)(adj[u] * scale);
    bin[u] = bi < 2047 ? bi : 2047;
    atomicAdd(&hist[bin[u]], 1u);
  }
  __syncthreads();
  unsigned int c[8];
  unsigned int local = 0;
#pragma unroll
  for (int q = 0; q < 8; q++) { c[q] = hist[t * 8 + q]; local += c[q]; }
  unsigned int incl = local;
#pragma unroll
  for (int off = 1; off < 64; off <<= 1) {
    unsigned int v = __shfl_up(incl, off, 64);
    if (lane >= off) incl += v;
  }
  if (lane == 63) wtot[wid] = incl;
  __syncthreads();
  unsigned int excl = incl - local;
  for (int w = 0; w < wid; w++) excl += wtot[w];
  if (excl < 30u && excl + local >= 30u) {
    unsigned int run = excl;
#pragma unroll
    for (int q = 0; q < 8; q++) {
      if (run + c[q] >= 30u) { s_bin = t * 8 + q; s_need = 30 - (int)run; break; }
      run += c[q];
    }
  }
  __syncthreads();
  const int tbin = s_bin;
  int pos[8];
#pragma unroll
  for (int u = 0; u < 8; u++) {
    pos[u] = -1;
    if (bin[u] == tbin) {
      int p = atomicAdd(&s_lcnt, 1);
      if (p < 64) { s_lkey[p] = __float_as_uint(adj[u]); s_lidx[p] = t + 256 * u; pos[u] = p; }
    }
  }
  __syncthreads();
  {
    int n = s_lcnt < 64 ? s_lcnt : 64;
    if (t < n) {
      unsigned int k0 = s_lkey[t];
      int j0 = s_lidx[t];
      int r = 0;
      for (int m = 0; m < n; m++) {
        unsigned int km = s_lkey[m];
        r += (km < k0) || (km == k0 && s_lidx[m] < j0);
      }
      s_sel[t] = (r < s_need) ? 1 : 0;
    }
  }
  __syncthreads();
#pragma unroll
  for (int u = 0; u < 8; u++) {
    bool sel = (bin[u] < tbin) || (pos[u] >= 0 && s_sel[pos[u]]);
    if (sel) {
      int o = atomicAdd(&s_outcnt, 1);
      if (o < 30) { sJ[o] = t + 256 * u; sD[o] = adj[u]; }
    }
  }
  __syncthreads();
  if (t < 30) Eidx[(size_t)row * 30 + t] = sJ[t];
  for (int o = t; o < 480; o += 256) {
    int k = o >> 4, s = o & 15;
    float mu = 2.0f + (4.0f / 3.0f) * (float)s;
    float z = (sD[k] - mu) * 0.8f;
    sRBF[k][s] = __expf(-z * z);
  }
  __syncthreads();
  if (t < 240) {
    int k = t >> 3, p = t & 7;
    int c0 = p * 2, c1 = c0 + 1;
    float e0 = 0.f, e1 = 0.f;
#pragma unroll
    for (int s = 0; s < 16; s++) {
      float r = sRBF[k][s];
      e0 += r * sWee[s][c0];
      e1 += r * sWee[s][c1];
    }
    float s1 = e0 + e1, s2 = e0 * e0 + e1 * e1;
#pragma unroll
    for (int m = 1; m < 8; m <<= 1) {
      s1 += __shfl_xor(s1, m, 64);
      s2 += __shfl_xor(s2, m, 64);
    }
    float mean = s1 * (1.f / 16.f);
    float var = s2 * (1.f / 16.f) - mean * mean;
    float inv = rsqrtf(var + 1e-5f);
    Eln[(size_t)row * 480 + k * 16 + c0] = __float2half((e0 - mean) * inv * sg[c0] + sb[c0]);
    Eln[(size_t)row * 480 + k * 16 + c1] = __float2half((e1 - mean) * inv * sg[c1] + sb[c1]);
  }
}

// ---------------- per-layer weight folding ----------------
__global__ __launch_bounds__(256) void k_prep(const float* __restrict__ Wep,
                                              const float* __restrict__ bep,
                                              const float* __restrict__ WK,
                                              const float* __restrict__ bK,
                                              const float* __restrict__ WV,
                                              const float* __restrict__ bV,
                                              float* __restrict__ WKfold,
                                              float* __restrict__ bK2,
                                              float* __restrict__ WepWV,
                                              float* __restrict__ bV2) {
  const int l = blockIdx.x >> 1, isV = blockIdx.x & 1;
  const float* W = (isV ? WV : WK) + (size_t)l * 8192;
  const float* bsrc = (isV ? bV : bK) + l * 64;
  float* fold = (isV ? WepWV : WKfold) + l * 1024;
  float* b2 = (isV ? bV2 : bK2) + l * 64;
  __shared__ float sW[64][64];
  __shared__ float sWep[16][64];
  const int t = threadIdx.x;
  for (int q = 0; q < 16; q++) { int i = t + 256 * q; sW[i >> 6][i & 63] = W[i]; }
  for (int q = 0; q < 4; q++)  { int i = t + 256 * q; sWep[i >> 6][i & 63] = Wep[i]; }
  __syncthreads();
  const int c = t & 63, rg = t >> 6;
  for (int r = rg; r < 16; r += 4) {
    float a = 0.f;
    for (int s = 0; s < 64; s++) a += sWep[r][s] * sW[s][c];
    fold[r * 64 + c] = a;
  }
  if (t < 64) {
    float a = bsrc[t];
    for (int s = 0; s < 64; s++) a += bep[s] * sW[s][t];
    b2[t] = a;
  }
}

// ---------------- k_qproj: fused Q=hV@WQ+bQ (LDS) -> QWn/eqw/qb2; 512 blocks x 32 rows ----------------
__global__ __launch_bounds__(256) void k_qproj(const float* __restrict__ hV,
                                               const float* __restrict__ WQ,
                                               const float* __restrict__ bQ,
                                               const float* __restrict__ WK,
                                               const float* __restrict__ WKfold,
                                               const float* __restrict__ bK2,
                                               float* __restrict__ QWn,
                                               float* __restrict__ eqw,
                                               float* __restrict__ qb2) {
  __shared__ float sX[32 * 68];
  __shared__ float sW[64 * 64];
  __shared__ float sb[64];
  const int t = threadIdx.x;
  const int row0 = blockIdx.x * 32;
  const int c = t & 63, rg = t >> 6;
  const int h = t >> 6, s2 = t & 63;
  const float4 wk0 = *(const float4*)&WK[(size_t)(64 + s2) * 64 + h * 16 + 0];
  const float4 wk1 = *(const float4*)&WK[(size_t)(64 + s2) * 64 + h * 16 + 4];
  const float4 wk2 = *(const float4*)&WK[(size_t)(64 + s2) * 64 + h * 16 + 8];
  const float4 wk3 = *(const float4*)&WK[(size_t)(64 + s2) * 64 + h * 16 + 12];
  const int rb4 = (t >> 4) & 3, tt = t & 15;
  const float4 wf0 = *(const float4*)&WKfold[tt * 64 + h * 16 + 0];
  const float4 wf1 = *(const float4*)&WKfold[tt * 64 + h * 16 + 4];
  const float4 wf2 = *(const float4*)&WKfold[tt * 64 + h * 16 + 8];
  const float4 wf3 = *(const float4*)&WKfold[tt * 64 + h * 16 + 12];
#pragma unroll
  for (int q = 0; q < 8; q++) {
    int i = t + 256 * q;
    sX[(i >> 6) * 68 + (i & 63)] = hV[(size_t)(row0 + (i >> 6)) * 64 + (i & 63)];
  }
#pragma unroll
  for (int q = 0; q < 16; q++) {
    int i = t + 256 * q;
    sW[i] = WQ[i];
  }
  if (t < 64) sb[t] = bK2[t];
  __syncthreads();
  float acc[8];
#pragma unroll
  for (int u = 0; u < 8; u++) acc[u] = 0.f;
#pragma unroll
  for (int s0 = 0; s0 < 64; s0 += 4) {
    float w0 = sW[s0 * 64 + c], w1 = sW[(s0 + 1) * 64 + c];
    float w2 = sW[(s0 + 2) * 64 + c], w3 = sW[(s0 + 3) * 64 + c];
#pragma unroll
    for (int u = 0; u < 8; u++) {
      const float4 a = *(const float4*)&sX[(rg + 4 * u) * 68 + s0];
      acc[u] += a.x * w0 + a.y * w1 + a.z * w2 + a.w * w3;
    }
  }
  __syncthreads();
  const float bb = bQ[c];
  float* sQ = sW;
#pragma unroll
  for (int u = 0; u < 8; u++) sQ[(rg + 4 * u) * 68 + c] = acc[u] + bb;
  __syncthreads();
  for (int r = 0; r < 32; r++) {
    const float4 q0 = *(const float4*)&sQ[r * 68 + h * 16 + 0];
    const float4 q1 = *(const float4*)&sQ[r * 68 + h * 16 + 4];
    const float4 q2 = *(const float4*)&sQ[r * 68 + h * 16 + 8];
    const float4 q3 = *(const float4*)&sQ[r * 68 + h * 16 + 12];
    float a = q0.x * wk0.x + q0.y * wk0.y + q0.z * wk0.z + q0.w * wk0.w
            + q1.x * wk1.x + q1.y * wk1.y + q1.z * wk1.z + q1.w * wk1.w
            + q2.x * wk2.x + q2.y * wk2.y + q2.z * wk2.z + q2.w * wk2.w
            + q3.x * wk3.x + q3.y * wk3.y + q3.z * wk3.z + q3.w * wk3.w;
    QWn[(size_t)(row0 + r) * 256 + h * 64 + s2] = a;
  }
  for (int rr = 0; rr < 8; rr++) {
    const int r = rr * 4 + rb4;
    const float4 q0 = *(const float4*)&sQ[r * 68 + h * 16 + 0];
    const float4 q1 = *(const float4*)&sQ[r * 68 + h * 16 + 4];
    const float4 q2 = *(const float4*)&sQ[r * 68 + h * 16 + 8];
    const float4 q3 = *(const float4*)&sQ[r * 68 + h * 16 + 12];
    float a = q0.x * wf0.x + q0.y * wf0.y + q0.z * wf0.z + q0.w * wf0.w
            + q1.x * wf1.x + q1.y * wf1.y + q1.z * wf1.z + q1.w * wf1.w
            + q2.x * wf2.x + q2.y * wf2.y + q2.z * wf2.z + q2.w * wf2.w
            + q3.x * wf3.x + q3.y * wf3.y + q3.z * wf3.z + q3.w * wf3.w;
    eqw[(size_t)(row0 + r) * 64 + h * 16 + tt] = a;
  }
  if (t < 128) {
    const int r = t >> 2, h2 = t & 3;
    float a = 0.f;
#pragma unroll
    for (int d = 0; d < 16; d++) a += sQ[r * 68 + h2 * 16 + d] * sb[h2 * 16 + d];
    qb2[(size_t)(row0 + r) * 4 + h2] = a;
  }
}

// ---------------- k_attn v4: float2 LDS (strides 66/18), split-k P-phase ----------------
__global__ __launch_bounds__(256) void k_attn(
    const __half* __restrict__ Eln, const int* __restrict__ Eidx,
    const float* __restrict__ hV, const float* __restrict__ mask,
    const float* __restrict__ QWn, const float* __restrict__ eqw,
    const float* __restrict__ qb2,
    float* __restrict__ Pg, float* __restrict__ attsum) {
  const int row = blockIdx.x;
  const int b = row >> 11;
  const int t = threadIdx.x;
  const int lane = t & 63, wid = t >> 6;
  __shared__ float sHV[30 * 66];
  __shared__ float sE[30 * 18];
  __shared__ float sQn[256];
  __shared__ float swq[64];
  __shared__ float sqb2[4];
  __shared__ float smk[32];
  __shared__ float satt4[32 * 4];
  __shared__ float sPc[4][4][64];
  __shared__ float sEc[4][4][16];

  sQn[t] = QWn[(size_t)row * 256 + t];
  if (t < 64) swq[t] = eqw[(size_t)row * 64 + t];
  if (t < 4) sqb2[t] = qb2[(size_t)row * 4 + t];
  if (t < 30) smk[t] = mask[(b << 11) + Eidx[(size_t)row * 30 + t]] * mask[row];
  if (t < 240) {
    const __half2 h2v = *(const __half2*)&Eln[(size_t)row * 480 + 2 * t];
    const float2 f2 = __half22float2(h2v);
    const int k = (2 * t) >> 4, c = (2 * t) & 15;
    *(float2*)&sE[k * 18 + c] = f2;
  }
#pragma unroll
  for (int q = 0; q < 4; q++) {
    int o = t + 256 * q;
    if (o < 960) {
      const int k = o >> 5, c2 = (o & 31) * 2;
      const int j = Eidx[(size_t)row * 30 + k];
      const float2 v = *(const float2*)&hV[((size_t)(b << 11) + j) * 64 + c2];
      *(float2*)&sHV[k * 66 + c2] = v;
    }
  }
  __syncthreads();

  const int kk = (lane < 30) ? lane : (lane - 30);
  const int sbase = (lane < 30) ? 0 : 32;
  const int tbase = (lane < 30) ? 0 : 8;
  float lg = 0.f;
  if (lane < 60) {
#pragma unroll
    for (int s = 0; s < 32; s += 2) {
      const float2 hv2 = *(const float2*)&sHV[kk * 66 + sbase + s];
      const float2 qn2 = *(const float2*)&sQn[wid * 64 + sbase + s];
      lg += hv2.x * qn2.x + hv2.y * qn2.y;
    }
#pragma unroll
    for (int tt = 0; tt < 8; tt += 2) {
      const float2 e2 = *(const float2*)&sE[kk * 18 + tbase + tt];
      const float2 w2 = *(const float2*)&swq[wid * 16 + tbase + tt];
      lg += e2.x * w2.x + e2.y * w2.y;
    }
  }
  float oth = __shfl(lg, lane + 30, 64);
  float mk = (lane < 30) ? smk[lane] : 0.f;
  float lgv = (lane < 30 && mk > 0.f) ? (lg + oth + sqb2[wid]) * 0.25f
                                      : -3.402823466e38f;
  float mx = lgv;
#pragma unroll
  for (int off = 16; off; off >>= 1) mx = fmaxf(mx, __shfl_xor(mx, off, 64));
  float e = (lane < 30) ? __expf(lgv - mx) : 0.f;
  float den = e;
#pragma unroll
  for (int off = 16; off; off >>= 1) den += __shfl_xor(den, off, 64);
  float att = e * (1.f / den) * mk;
  float ss = att;
#pragma unroll
  for (int off = 16; off; off >>= 1) ss += __shfl_xor(ss, off, 64);
  if (lane == 0) attsum[(size_t)row * 4 + wid] = ss;
  if (lane < 30) satt4[lane * 4 + wid] = att;
  __syncthreads();

  const int k0 = wid * 8;
  const int knum = (wid == 3) ? 6 : 8;
  float pn0 = 0.f, pn1 = 0.f, pn2 = 0.f, pn3 = 0.f;
  float ea0 = 0.f, ea1 = 0.f, ea2 = 0.f, ea3 = 0.f;
  for (int u = 0; u < knum; u++) {
    const int k2 = k0 + u;
    const float4 a4 = *(const float4*)&satt4[k2 * 4];
    const float hvv = sHV[k2 * 66 + lane];
    pn0 += a4.x * hvv; pn1 += a4.y * hvv; pn2 += a4.z * hvv; pn3 += a4.w * hvv;
    const float ev = (lane < 16) ? sE[k2 * 18 + lane] : 0.f;
    ea0 += a4.x * ev; ea1 += a4.y * ev; ea2 += a4.z * ev; ea3 += a4.w * ev;
  }
  sPc[wid][0][lane] = pn0;
  sPc[wid][1][lane] = pn1;
  sPc[wid][2][lane] = pn2;
  sPc[wid][3][lane] = pn3;
  if (lane < 16) {
    sEc[wid][0][lane] = ea0;
    sEc[wid][1][lane] = ea1;
    sEc[wid][2][lane] = ea2;
    sEc[wid][3][lane] = ea3;
  }
  __syncthreads();
  float pv = sPc[0][wid][lane] + sPc[1][wid][lane] + sPc[2][wid][lane] + sPc[3][wid][lane];
  float* pr = Pg + (size_t)row * 320 + wid * 80;
  pr[lane] = pv;
  if (lane < 16) {
    float ev2 = sEc[0][wid][lane] + sEc[1][wid][lane] + sEc[2][wid][lane] + sEc[3][wid][lane];
    pr[64 + lane] = ev2;
  }
}

// ---------------- k_updln: U = P@WV'(+bias) in LDS, then hV = LN(hV + U@WO + bO) ----------------
// 8 rows/block, 2048 blocks, ~49 KB LDS -> 3 blocks/CU (lean version; NOT R5's 63 KB variant)
__global__ __launch_bounds__(256) void k_updln(const float* __restrict__ Pg,
                                               const float* __restrict__ ats,
                                               const float* __restrict__ WV,
                                               const float* __restrict__ WepWV,
                                               const float* __restrict__ bV2,
                                               const float* __restrict__ WO,
                                               const float* __restrict__ bO,
                                               const float* __restrict__ g,
                                               const float* __restrict__ bb_,
                                               float* __restrict__ hV) {
  __shared__ float sWVb[64 * 64];
  __shared__ float sWf[16 * 64];
  __shared__ float sWO[64 * 64];
  __shared__ float sP[8 * 320];
  __shared__ float sU[8 * 68];
  __shared__ float sbV2[64], sbO[64], sg[64], sbb[64], sats[32];
  const int t = threadIdx.x;
  const int row0 = blockIdx.x * 8;
  for (int q = 0; q < 16; q++) { int i = t + 256 * q; sWVb[i] = WV[4096 + i]; }
  for (int q = 0; q < 4; q++)  { int i = t + 256 * q; sWf[i] = WepWV[i]; }
  for (int q = 0; q < 16; q++) { int i = t + 256 * q; sWO[i] = WO[i]; }
  for (int q = 0; q < 10; q++) { int i = t + 256 * q; sP[i] = Pg[(size_t)row0 * 320 + i]; }
  if (t < 64) {
    sbV2[t] = bV2[t];
    sbO[t] = bO[t];
    sg[t] = g[t];
    sbb[t] = bb_[t];
  }
  if (t < 32) sats[t] = ats[(size_t)row0 * 4 + t];
  __syncthreads();
  const int c = t & 63, rg = t >> 6;
  const int h = c >> 4;
  const int r0 = rg * 2;
  float a0 = 0.f, a1 = 0.f;
#pragma unroll 8
  for (int s = 0; s < 64; s++) {
    float w = sWVb[s * 64 + c];
    a0 += sP[r0 * 320 + h * 80 + s] * w;
    a1 += sP[(r0 + 1) * 320 + h * 80 + s] * w;
  }
#pragma unroll
  for (int tt = 0; tt < 16; tt++) {
    float w = sWf[tt * 64 + c];
    a0 += sP[r0 * 320 + h * 80 + 64 + tt] * w;
    a1 += sP[(r0 + 1) * 320 + h * 80 + 64 + tt] * w;
  }
  const float bv = sbV2[c];
  sU[r0 * 68 + c] = a0 + sats[r0 * 4 + h] * bv;
  sU[(r0 + 1) * 68 + c] = a1 + sats[(r0 + 1) * 4 + h] * bv;
  __syncthreads();
  // phase 2: hV = LN(hV + U @ WO + bO); lanes = cols, waves cover rows
  const int lane = t & 63, wv = t >> 6;
  const float gv = sg[lane], bbv = sbb[lane];
#pragma unroll
  for (int r = wv; r < 8; r += 4) {
    const int row = row0 + r;
    float a = sbO[lane];
#pragma unroll 8
    for (int cc = 0; cc < 64; cc++) a += sU[r * 68 + cc] * sWO[cc * 64 + lane];
    float x = hV[(size_t)row * 64 + lane] + a;
    float s1 = x, s2 = x * x;
#pragma unroll
    for (int off = 32; off; off >>= 1) {
      s1 += __shfl_xor(s1, off, 64);
      s2 += __shfl_xor(s2, off, 64);
    }
    float m = s1 * (1.f / 64.f);
    float var = s2 * (1.f / 64.f) - m * m;
    float inv = rsqrtf(var + 1e-5f);
    hV[(size_t)row * 64 + lane] = (x - m) * inv * gv + bbv;
  }
}

// ---------------- T = relu(hV @ W1 + bf1) ----------------
__global__ __launch_bounds__(256) void k_ffn1(const float* __restrict__ X,
                                              const float* __restrict__ W1,
                                              const float* __restrict__ bf1,
                                              float* __restrict__ T) {
  __shared__ float sXt[64][16];
  __shared__ float sW[32][256];
  const int t = threadIdx.x;
  const int row0 = blockIdx.x * 16;
#pragma unroll
  for (int q = 0; q < 4; q++) {
    int i = t + 256 * q;
    int r = i >> 6, cc = i & 63;
    sXt[cc][r] = X[(size_t)(row0 + r) * 64 + cc];
  }
  float acc[16];
#pragma unroll
  for (int u = 0; u < 16; u++) acc[u] = 0.f;
  for (int kc = 0; kc < 64; kc += 32) {
    __syncthreads();
#pragma unroll
    for (int q = 0; q < 32; q++) {
      int i = t + 256 * q;
      sW[i >> 8][i & 255] = W1[(size_t)(kc + (i >> 8)) * 256 + (i & 255)];
    }
    __syncthreads();
#pragma unroll
    for (int s = 0; s < 32; s++) {
      float w = sW[s][t];
      const float4 x0 = *(const float4*)&sXt[kc + s][0];
      const float4 x1 = *(const float4*)&sXt[kc + s][4];
      const float4 x2 = *(const float4*)&sXt[kc + s][8];
      const float4 x3 = *(const float4*)&sXt[kc + s][12];
      acc[0] += x0.x * w; acc[1] += x0.y * w; acc[2] += x0.z * w; acc[3] += x0.w * w;
      acc[4] += x1.x * w; acc[5] += x1.y * w; acc[6] += x1.z * w; acc[7] += x1.w * w;
      acc[8] += x2.x * w; acc[9] += x2.y * w; acc[10] += x2.z * w; acc[11] += x2.w * w;
      acc[12] += x3.x * w; acc[13] += x3.y * w; acc[14] += x3.z * w; acc[15] += x3.w * w;
    }
  }
  const float bv = bf1[t];
#pragma unroll
  for (int r = 0; r < 16; r++)
    T[(size_t)(row0 + r) * 256 + t] = fmaxf(acc[r] + bv, 0.f);
}

// ---------------- hV = LN(hV + T @ W2 + bf2) * mask ----------------
__global__ __launch_bounds__(256) void k_ffn2(const float* __restrict__ T,
                                              const float* __restrict__ W2,
                                              const float* __restrict__ bf2,
                                              const float* __restrict__ g,
                                              const float* __restrict__ bb,
                                              const float* __restrict__ mask,
                                              float* __restrict__ hV) {
  __shared__ float sTt[64][16];
  __shared__ float sW[64][64];
  __shared__ float sO[16][64];
  const int t = threadIdx.x;
  const int row0 = blockIdx.x * 16;
  const int c = t & 63, rg = t >> 6;
  float acc[4] = {0.f, 0.f, 0.f, 0.f};
  for (int kc = 0; kc < 256; kc += 64) {
    __syncthreads();
#pragma unroll
    for (int q = 0; q < 4; q++) {
      int i = t + 256 * q;
      int r = i >> 6, cc = i & 63;
      sTt[cc][r] = T[(size_t)(row0 + r) * 256 + kc + cc];
    }
#pragma unroll
    for (int q = 0; q < 16; q++) {
      int i = t + 256 * q;
      sW[i >> 6][i & 63] = W2[(size_t)(kc + (i >> 6)) * 64 + (i & 63)];
    }
    __syncthreads();
#pragma unroll
    for (int s = 0; s < 64; s++) {
      float w = sW[s][c];
      const float4 x = *(const float4*)&sTt[s][rg * 4];
      acc[0] += x.x * w; acc[1] += x.y * w; acc[2] += x.z * w; acc[3] += x.w * w;
    }
  }
  const float bv = bf2[c];
#pragma unroll
  for (int u = 0; u < 4; u++) sO[rg * 4 + u][c] = acc[u] + bv;
  __syncthreads();
  const int lane = t & 63, wv = t >> 6;
  const float gv = g[lane], bbv = bb[lane];
  for (int r = wv; r < 16; r += 4) {
    const int row = row0 + r;
    float x = hV[(size_t)row * 64 + lane] + sO[r][lane];
    float s1 = x, s2 = x * x;
#pragma unroll
    for (int off = 32; off; off >>= 1) {
      s1 += __shfl_xor(s1, off, 64);
      s2 += __shfl_xor(s2, off, 64);
    }
    float m = s1 * (1.f / 64.f);
    float var = s2 * (1.f / 64.f) - m * m;
    float inv = rsqrtf(var + 1e-5f);
    float y = (x - m) * inv * gv + bbv;
    hV[(size_t)row * 64 + lane] = y * mask[row];
  }
}

// ---------------- out = hV @ W_out + b_out ----------------
__global__ __launch_bounds__(256) void k_out(const float* __restrict__ hV,
                                             const float* __restrict__ Wo,
                                             const float* __restrict__ bo,
                                             float* __restrict__ out) {
  const int t = threadIdx.x;
  const int lane = t & 63, wv = t >> 6;
  const int row = blockIdx.x * 4 + wv;
  float v = hV[(size_t)row * 64 + lane] * Wo[lane];
#pragma unroll
  for (int off = 32; off; off >>= 1) v += __shfl_xor(v, off, 64);
  if (lane == 0) out[row] = v + bo[0];
}

extern "C" void kernel_launch(void* const* d_in, const int* in_sizes, int n_in,
                              void* d_out, int out_size, void* d_ws, size_t ws_size,
                              hipStream_t stream) {
  const float* coords = (const float*)d_in[0];
  const float* nodef = (const float*)d_in[1];
  const float* mask = (const float*)d_in[2];
  const float* W_node = (const float*)d_in[3];
  const float* b_node = (const float*)d_in[4];
  const float* W_ee = (const float*)d_in[5];
  const float* g_eln = (const float*)d_in[6];
  const float* b_eln = (const float*)d_in[7];
  const float* W_ep = (const float*)d_in[8];
  const float* b_ep = (const float*)d_in[9];
  const float* WQ = (const float*)d_in[10];
  const float* bQ = (const float*)d_in[11];
  const float* WK = (const float*)d_in[12];
  const float* bK = (const float*)d_in[13];
  const float* WV = (const float*)d_in[14];
  const float* bV = (const float*)d_in[15];
  const float* WO = (const float*)d_in[16];
  const float* bO = (const float*)d_in[17];
  const float* g1 = (const float*)d_in[18];
  const float* b1 = (const float*)d_in[19];
  const float* W1 = (const float*)d_in[20];
  const float* bf1 = (const float*)d_in[21];
  const float* W2 = (const float*)d_in[22];
  const float* bf2 = (const float*)d_in[23];
  const float* g2 = (const float*)d_in[24];
  const float* b2 = (const float*)d_in[25];
  const float* W_out = (const float*)d_in[26];
  const float* b_out = (const float*)d_in[27];

  float* ws = (float*)d_ws;
  float* hV = ws;                           // 1,048,576 f
  float* Qb = hV + 1048576;                 // 1,048,576 f  (unused now, kept for layout stability)
  float* QWn = Qb + 1048576;                // 4,194,304 f  (alias Tb)
  float* eqw = QWn + 4194304;               // 1,048,576 f
  float* Pg = eqw + 1048576;                // 5,242,880 f  (alias Part)
  float* qb2 = Pg + 5242880;                // 65,536 f
  float* ats = qb2 + 65536;                 // 65,536 f
  int* Eidx = (int*)(ats + 65536);          // 491,520 i
  __half* Eln = (__half*)(Eidx + 491520);   // 7,864,320 h
  float* WKfold = (float*)(Eln + 7864320);  // 4,096 f
  float* bK2 = WKfold + 4096;               // 256 f
  float* WepWV = bK2 + 256;                 // 4,096 f
  float* bV2 = WepWV + 4096;                // 256 f
  float* Tb = QWn;                          // alias: lifetime disjoint
  float* Part = Pg;                         // alias: k_node partials

  k_node_part<<<512, 256, 0, stream>>>(nodef, W_node, Part);
  k_node_sum<<<1024, 256, 0, stream>>>(Part, b_node, hV);
  k_edges<<<16384, 256, 0, stream>>>(coords, mask, W_ee, g_eln, b_eln, Eidx, Eln);
  k_prep<<<8, 256, 0, stream>>>(W_ep, b_ep, WK, bK, WV, bV, WKfold, bK2, WepWV, bV2);
  for (int l = 0; l < 4; l++) {
    k_qproj<<<512, 256, 0, stream>>>(hV, WQ + l * 4096, bQ + l * 64,
                                     WK + l * 8192, WKfold + l * 1024, bK2 + l * 64,
                                     QWn, eqw, qb2);
    k_attn<<<16384, 256, 0, stream>>>(Eln, Eidx, hV, mask, QWn, eqw, qb2, Pg, ats);
    k_updln<<<2048, 256, 0, stream>>>(Pg, ats, WV + l * 8192, WepWV + l * 1024,
                                      bV2 + l * 64, WO + l * 4096, bO + l * 64,
                                      g1 + l * 64, b1 + l * 64, hV);
    k_ffn1<<<1024, 256, 0, stream>>>(hV, W1 + l * 16384, bf1 + l * 256, Tb);
    k_ffn2<<<1024, 256, 0, stream>>>(Tb, W2 + l * 16384, bf2 + l * 64,
                                     g2 + l * 64, b2 + l * 64, mask, hV);
  }
  k_out<<<4096, 256, 0, stream>>>(hV, W_out, b_out, (float*)d_out);
}